// Round 4
// baseline (12762.782 us; speedup 1.0000x reference)
//
#include <hip/hip_runtime.h>
#include <hip/hip_bf16.h>

constexpr int B = 4, T = 512, F = 352, CF = 16, HD = 128, F4 = 88;
constexpr int PLANE  = T * F;    // 180224
constexpr int PLANE4 = T * F4;   // 45056
constexpr int NDIL = 8;

// ---------------- prep: pack harmonic-dilated weights ----------------
// Wp[o][i][17] = { wc (sum of center taps), wl[0..7], wr[0..7] }, bsum[o] = sum_d b_hd[d][o]
__global__ void prep_hd(const float* __restrict__ w_hd, const float* __restrict__ b_hd,
                        float* __restrict__ Wp, float* __restrict__ bsum) {
    int tid = blockIdx.x * blockDim.x + threadIdx.x;
    if (tid >= HD * CF) return;
    int o = tid / CF, i = tid % CF;
    float wc = 0.f;
    float* dst = Wp + (o * CF + i) * 17;
    for (int d = 0; d < NDIL; ++d) {
        const float* w = w_hd + ((d * HD + o) * CF + i) * 3;
        wc += w[1];
        dst[1 + d] = w[0];
        dst[9 + d] = w[2];
    }
    dst[0] = wc;
    if (i == 0) {
        float bs = 0.f;
        for (int d = 0; d < NDIL; ++d) bs += b_hd[d * HD + o];
        bsum[o] = bs;
    }
}

// ---------------- 7x7 conv + relu, 16 couts per thread ----------------
template<int CIN>
__global__ __launch_bounds__(256) void conv7x7_relu(
        const float* __restrict__ x, const float* __restrict__ w,
        const float* __restrict__ bias, float* __restrict__ out) {
    int idx = blockIdx.x * 256 + threadIdx.x;      // over B*T*F, f fastest
    int f = idx % F;
    int t = (idx / F) % T;
    int n = idx / (F * T);
    float acc[CF];
#pragma unroll
    for (int co = 0; co < CF; ++co) acc[co] = bias[co];
    for (int ci = 0; ci < CIN; ++ci) {
        const float* xp = x + (n * CIN + ci) * PLANE;
        float xv[49];
#pragma unroll
        for (int dy = 0; dy < 7; ++dy) {
            int tt = t + dy - 3;
            bool tok = (unsigned)tt < (unsigned)T;
#pragma unroll
            for (int dx = 0; dx < 7; ++dx) {
                int ff = f + dx - 3;
                xv[dy * 7 + dx] = (tok && (unsigned)ff < (unsigned)F) ? xp[tt * F + ff] : 0.f;
            }
        }
#pragma unroll
        for (int co = 0; co < CF; ++co) {
            const float* wpc = w + (co * CIN + ci) * 49;   // wave-uniform -> s_load
#pragma unroll
            for (int k = 0; k < 49; ++k) acc[co] = fmaf(xv[k], wpc[k], acc[co]);
        }
    }
    float* op = out + n * CF * PLANE + t * F + f;
#pragma unroll
    for (int co = 0; co < CF; ++co) op[co * PLANE] = fmaxf(acc[co], 0.f);
}

// ---------------- fused: 8-dilation hd_conv -> LDS(bf16) -> wd0(1x3 d48)+relu+pool4 ----------------
// One workgroup per (n,t) row. LDS holds y_row[128][352] bf16 = 90112 B (dynamic).
__global__ __launch_bounds__(512) void hd_wd0_fused(
        const float* __restrict__ x,    // [B,16,T,F] (normed conv stack out)
        const float* __restrict__ Wp,   // [128][16][17] packed
        const float* __restrict__ bsum, // [128]
        const float* __restrict__ wd0,  // [128][128][3]
        const float* __restrict__ bd0,  // [128]
        float* __restrict__ z) {        // [B,128,T,88]
    extern __shared__ __hip_bfloat16 ylds[];   // [HD][F]
    const int n = blockIdx.x / T, t = blockIdx.x % T;
    const int lane = threadIdx.x & 63;
    const int wid  = threadIdx.x >> 6;         // 0..7
    const int DIL[NDIL] = {48, 76, 96, 111, 124, 135, 144, 152};

    // ---- phase 1: y_row = sum of 8 dilated 1x3 convs over x row t ----
    // wave-items: 8 og-groups x 6 f-chunks of 64 (f<352 guard)
    for (int w = wid; w < 48; w += 8) {
        int og = __builtin_amdgcn_readfirstlane(w / 6);
        int fc = __builtin_amdgcn_readfirstlane(w % 6);
        int f = fc * 64 + lane;
        bool fok = f < F;
        float acc[16];
#pragma unroll
        for (int j = 0; j < 16; ++j) acc[j] = bsum[og * 16 + j];
        for (int ci = 0; ci < CF; ++ci) {
            const float* xp = x + (size_t)(n * CF + ci) * PLANE + t * F;
            float xv[17];
            xv[0] = fok ? xp[f] : 0.f;
#pragma unroll
            for (int d = 0; d < NDIL; ++d) {
                int fl = f - DIL[d], fr = f + DIL[d];
                xv[1 + d] = (fok && fl >= 0) ? xp[fl] : 0.f;
                xv[9 + d] = (fok && fr < F)  ? xp[fr] : 0.f;
            }
            const float* wp0 = Wp + (og * 16 * CF + ci) * 17;   // og uniform -> s_load
#pragma unroll
            for (int j = 0; j < 16; ++j) {
                const float* wp = wp0 + j * CF * 17;
#pragma unroll
                for (int k = 0; k < 17; ++k) acc[j] = fmaf(xv[k], wp[k], acc[j]);
            }
        }
        if (fok) {
#pragma unroll
            for (int j = 0; j < 16; ++j)
                ylds[(og * 16 + j) * F + f] = __float2bfloat16(acc[j]);
        }
    }
    __syncthreads();

    // ---- phase 2: wd0 1x3 dil48 over LDS row + relu + maxpool(1,4) ----
    for (int w = wid; w < 48; w += 8) {
        int og = __builtin_amdgcn_readfirstlane(w / 6);
        int fc = __builtin_amdgcn_readfirstlane(w % 6);
        int f = fc * 64 + lane;
        bool fok = f < F;
        float acc[16];
#pragma unroll
        for (int j = 0; j < 16; ++j) acc[j] = bd0[og * 16 + j];
        for (int ci = 0; ci < HD; ++ci) {
            const __hip_bfloat16* yp = ylds + ci * F;
            float x0 = (fok && f >= 48)    ? __bfloat162float(yp[f - 48]) : 0.f;
            float x1 = fok                 ? __bfloat162float(yp[f])      : 0.f;
            float x2 = (fok && f + 48 < F) ? __bfloat162float(yp[f + 48]) : 0.f;
            const float* wp0 = wd0 + (og * 16 * HD + ci) * 3;   // og uniform -> s_load
#pragma unroll
            for (int j = 0; j < 16; ++j) {
                const float* wp = wp0 + j * HD * 3;
                acc[j] = fmaf(x0, wp[0], fmaf(x1, wp[1], fmaf(x2, wp[2], acc[j])));
            }
        }
#pragma unroll
        for (int j = 0; j < 16; ++j) {
            float v = fmaxf(acc[j], 0.f);
            v = fmaxf(v, __shfl_xor(v, 1));
            v = fmaxf(v, __shfl_xor(v, 2));
            acc[j] = v;
        }
        if (fok && (lane & 3) == 0) {
            float* zp = z + (size_t)(n * HD + og * 16) * PLANE4 + t * F4 + (f >> 2);
#pragma unroll
            for (int j = 0; j < 16; ++j) zp[j * PLANE4] = acc[j];
        }
    }
}

// ---------------- wd1: 1x3 dil 12 + relu on [4,128,T,88] ----------------
__global__ __launch_bounds__(256) void wd_1x3d12_relu(
        const float* __restrict__ zin, const float* __restrict__ w,
        const float* __restrict__ bias, float* __restrict__ zout) {
    int idx = blockIdx.x * 256 + threadIdx.x;      // over B*(HD/16)*T*F4
    int f = idx % F4;
    int t = (idx / F4) % T;
    int og = (idx / PLANE4) % (HD / 16);
    int n = idx / (PLANE4 * (HD / 16));
    float acc[16];
#pragma unroll
    for (int j = 0; j < 16; ++j) acc[j] = bias[og * 16 + j];
    for (int ci = 0; ci < HD; ++ci) {
        const float* zp = zin + (n * HD + ci) * PLANE4 + t * F4;
        float x0 = (f >= 12)     ? zp[f - 12] : 0.f;
        float x1 =                 zp[f];
        float x2 = (f + 12 < F4) ? zp[f + 12] : 0.f;
#pragma unroll
        for (int j = 0; j < 16; ++j) {
            const float* wp = w + ((og * 16 + j) * HD + ci) * 3;
            acc[j] = fmaf(x0, wp[0], fmaf(x1, wp[1], fmaf(x2, wp[2], acc[j])));
        }
    }
    float* zp = zout + (n * HD + og * 16) * PLANE4 + t * F4 + f;
#pragma unroll
    for (int j = 0; j < 16; ++j) zp[j * PLANE4] = fmaxf(acc[j], 0.f);
}

// ---------------- wd2/3/4: 5x1 (time) pad 2 + relu ----------------
__global__ __launch_bounds__(256) void wd_5x1_relu(
        const float* __restrict__ zin, const float* __restrict__ w,
        const float* __restrict__ bias, float* __restrict__ zout) {
    int idx = blockIdx.x * 256 + threadIdx.x;      // over B*(HD/16)*T*F4
    int f = idx % F4;
    int t = (idx / F4) % T;
    int og = (idx / PLANE4) % (HD / 16);
    int n = idx / (PLANE4 * (HD / 16));
    float acc[16];
#pragma unroll
    for (int j = 0; j < 16; ++j) acc[j] = bias[og * 16 + j];
    for (int ci = 0; ci < HD; ++ci) {
        const float* zp = zin + (n * HD + ci) * PLANE4 + f;
        float xv[5];
#pragma unroll
        for (int dt = 0; dt < 5; ++dt) {
            int tt = t + dt - 2;
            xv[dt] = ((unsigned)tt < (unsigned)T) ? zp[tt * F4] : 0.f;
        }
#pragma unroll
        for (int j = 0; j < 16; ++j) {
            const float* wp = w + ((og * 16 + j) * HD + ci) * 5;
#pragma unroll
            for (int dt = 0; dt < 5; ++dt) acc[j] = fmaf(xv[dt], wp[dt], acc[j]);
        }
    }
    float* zp = zout + (n * HD + og * 16) * PLANE4 + t * F4 + f;
#pragma unroll
    for (int j = 0; j < 16; ++j) zp[j * PLANE4] = fmaxf(acc[j], 0.f);
}

// ---------------- instance norm: partial stats -> finalize -> apply ----------------
__global__ __launch_bounds__(256) void inorm_stats(const float* __restrict__ x,
                                                   float* __restrict__ part,
                                                   int plane, int nchunks) {
    int p = blockIdx.x / nchunks, c = blockIdx.x % nchunks;
    int len = plane / nchunks;                     // exact by construction
    const float4* xp = (const float4*)(x + (size_t)p * plane + (size_t)c * len);
    int n4 = len / 4;
    float s = 0.f, q = 0.f;
    for (int i = threadIdx.x; i < n4; i += 256) {
        float4 v = xp[i];
        s += v.x + v.y + v.z + v.w;
        q += v.x * v.x + v.y * v.y + v.z * v.z + v.w * v.w;
    }
#pragma unroll
    for (int off = 32; off > 0; off >>= 1) {
        s += __shfl_down(s, off);
        q += __shfl_down(q, off);
    }
    __shared__ float ss[4], qq[4];
    int wid = threadIdx.x >> 6;
    if ((threadIdx.x & 63) == 0) { ss[wid] = s; qq[wid] = q; }
    __syncthreads();
    if (threadIdx.x == 0) {
        s = ss[0] + ss[1] + ss[2] + ss[3];
        q = qq[0] + qq[1] + qq[2] + qq[3];
        part[blockIdx.x * 2]     = s;
        part[blockIdx.x * 2 + 1] = q;
    }
}

__global__ void inorm_finalize(const float* __restrict__ part, float* __restrict__ mean,
                               float* __restrict__ rstd, int nplanes, int nchunks,
                               float inv_plane) {
    int p = blockIdx.x * blockDim.x + threadIdx.x;
    if (p >= nplanes) return;
    float s = 0.f, q = 0.f;
    for (int c = 0; c < nchunks; ++c) {
        s += part[(p * nchunks + c) * 2];
        q += part[(p * nchunks + c) * 2 + 1];
    }
    float m = s * inv_plane;
    float v = q * inv_plane - m * m;
    mean[p] = m;
    rstd[p] = rsqrtf(v + 1e-5f);
}

template<int PSIZE>
__global__ __launch_bounds__(256) void inorm_apply(const float* __restrict__ in,
                                                   float* __restrict__ out,
                                                   const float* __restrict__ mean,
                                                   const float* __restrict__ rstd) {
    int i4 = blockIdx.x * 256 + threadIdx.x;
    int p = (i4 * 4) / PSIZE;
    float m = mean[p], r = rstd[p];
    float4 v = ((const float4*)in)[i4];
    v.x = (v.x - m) * r; v.y = (v.y - m) * r; v.z = (v.z - m) * r; v.w = (v.w - m) * r;
    ((float4*)out)[i4] = v;
}

// ---------------- launcher ----------------
extern "C" void kernel_launch(void* const* d_in, const int* in_sizes, int n_in,
                              void* d_out, int out_size, void* d_ws, size_t ws_size,
                              hipStream_t stream) {
    (void)in_sizes; (void)n_in; (void)out_size; (void)ws_size;
    const float* cqt  = (const float*)d_in[0];
    const float* w0   = (const float*)d_in[1];  const float* b0  = (const float*)d_in[2];
    const float* w1   = (const float*)d_in[3];  const float* b1  = (const float*)d_in[4];
    const float* w2   = (const float*)d_in[5];  const float* b2  = (const float*)d_in[6];
    const float* w_hd = (const float*)d_in[7];  const float* bhd = (const float*)d_in[8];
    const float* wd0  = (const float*)d_in[9];  const float* bd0 = (const float*)d_in[10];
    const float* wd1  = (const float*)d_in[11]; const float* bd1 = (const float*)d_in[12];
    const float* wd2  = (const float*)d_in[13]; const float* bd2 = (const float*)d_in[14];
    const float* wd3  = (const float*)d_in[15]; const float* bd3 = (const float*)d_in[16];
    const float* wd4  = (const float*)d_in[17]; const float* bd4 = (const float*)d_in[18];
    float* out = (float*)d_out;

    // workspace layout (~138.6 MB total; x2 aliases the z ping-pong buffer)
    float* x1   = (float*)d_ws;                    // 11,534,336 f  (46.1 MB)
    float* zb   = x1 + (size_t)B * CF * PLANE;     // 23,068,672 f  (92.3 MB)
    float* x2   = zb;                              // alias: dead before zb written
    float* Wp   = zb + (size_t)B * HD * PLANE4;    // 34,816 f
    float* bsum = Wp + HD * CF * 17;               // 128 f
    float* part = bsum + HD;                       // 4096 f
    float* meanb = part + 4096;                    // 512 f
    float* rstdb = meanb + 512;                    // 512 f

    auto norm_big = [&](float* bin, float* bout) {   // 64 planes of PLANE
        inorm_stats<<<64 * 8, 256, 0, stream>>>(bin, part, PLANE, 8);
        inorm_finalize<<<1, 64, 0, stream>>>(part, meanb, rstdb, 64, 8, 1.f / PLANE);
        inorm_apply<PLANE><<<64 * PLANE / 4 / 256, 256, 0, stream>>>(bin, bout, meanb, rstdb);
    };
    auto norm_z = [&](float* bin, float* bout) {     // 512 planes of PLANE4
        inorm_stats<<<512 * 4, 256, 0, stream>>>(bin, part, PLANE4, 4);
        inorm_finalize<<<1, 512, 0, stream>>>(part, meanb, rstdb, 512, 4, 1.f / PLANE4);
        inorm_apply<PLANE4><<<512 * PLANE4 / 4 / 256, 256, 0, stream>>>(bin, bout, meanb, rstdb);
    };

    prep_hd<<<8, 256, 0, stream>>>(w_hd, bhd, Wp, bsum);

    conv7x7_relu<1><<<B * T * F / 256, 256, 0, stream>>>(cqt, w0, b0, x1);
    norm_big(x1, x1);
    conv7x7_relu<16><<<B * T * F / 256, 256, 0, stream>>>(x1, w1, b1, x2);
    norm_big(x2, x2);
    conv7x7_relu<16><<<B * T * F / 256, 256, 0, stream>>>(x2, w2, b2, x1);
    norm_big(x1, x1);

    // fused hd_conv + wd0 + relu + maxpool: x1 -> zb (clobbers x2 alias, which is dead)
    hd_wd0_fused<<<B * T, 512, HD * F * (int)sizeof(__hip_bfloat16), stream>>>(
        x1, Wp, bsum, wd0, bd0, zb);
    norm_z(zb, zb);

    wd_1x3d12_relu<<<B * (HD / 16) * T * F4 / 256, 256, 0, stream>>>(zb, wd1, bd1, out);
    norm_z(out, out);
    wd_5x1_relu<<<B * (HD / 16) * T * F4 / 256, 256, 0, stream>>>(out, wd2, bd2, zb);
    norm_z(zb, zb);
    wd_5x1_relu<<<B * (HD / 16) * T * F4 / 256, 256, 0, stream>>>(zb, wd3, bd3, out);
    norm_z(out, out);
    wd_5x1_relu<<<B * (HD / 16) * T * F4 / 256, 256, 0, stream>>>(out, wd4, bd4, zb);
    norm_z(zb, out);
}

// Round 6
// 3044.041 us; speedup vs baseline: 4.1927x; 4.1927x over previous
//
#include <hip/hip_runtime.h>
#include <hip/hip_bf16.h>

constexpr int B = 4, T = 512, F = 352, CF = 16, HD = 128, F4 = 88;
constexpr int PLANE  = T * F;    // 180224
constexpr int PLANE4 = T * F4;   // 45056
constexpr int NDIL = 8;

typedef __attribute__((ext_vector_type(8))) short short8;
typedef __attribute__((ext_vector_type(4))) float f32x4;
typedef unsigned short u16;
typedef unsigned long long u64;

#define MFMA(a, b, c) __builtin_amdgcn_mfma_f32_16x16x32_bf16(a, b, c, 0, 0, 0)

__device__ inline u16 f2bf(float x) {
    unsigned u = __float_as_uint(x);
    return (u16)((u + 0x7fffu + ((u >> 16) & 1u)) >> 16);
}

// ======================= weight packing =======================
// A-frag layout (M=cout): value(og,chunk,lane,e) = W[og*16 + (lane&15)][k = chunk*32 + (lane>>4)*8 + e]
// hd: k -> tau = k>>4 (18 taps: [sumcenter, left d0..7, right d0..7, zero]), ci = k&15
__global__ void prep_hd_pack(const float* __restrict__ w_hd, const float* __restrict__ b_hd,
                             u16* __restrict__ WpP, float* __restrict__ bsum) {
    int tid = blockIdx.x * 256 + threadIdx.x;
    if (tid < HD) {
        float s = 0.f;
        for (int d = 0; d < NDIL; ++d) s += b_hd[d * HD + tid];
        bsum[tid] = s;
    }
    if (tid >= 8 * 9 * 64) return;
    int l = tid & 63, c = (tid >> 6) % 9, og = tid / (9 * 64);
    int cout = og * 16 + (l & 15);
#pragma unroll
    for (int e = 0; e < 8; ++e) {
        int k = c * 32 + ((l >> 4) * 8) + e;
        int tau = k >> 4, ci = k & 15;
        float v = 0.f;
        if (tau == 0) {
            for (int d = 0; d < NDIL; ++d) v += w_hd[((d * HD + cout) * CF + ci) * 3 + 1];
        } else if (tau <= 8) {
            v = w_hd[(((tau - 1) * HD + cout) * CF + ci) * 3 + 0];
        } else if (tau <= 16) {
            v = w_hd[(((tau - 9) * HD + cout) * CF + ci) * 3 + 2];
        }
        WpP[tid * 8 + e] = f2bf(v);
    }
}

// wd convs: k -> tau = k>>7, ci = k&127; src layout [cout][ci][ntap]
__global__ void pack_wd(const float* __restrict__ wsrc, u16* __restrict__ dst,
                        int ntap, int nch) {
    int tid = blockIdx.x * 256 + threadIdx.x;
    if (tid >= 8 * nch * 64) return;
    int l = tid & 63, c = (tid >> 6) % nch, og = tid / (nch * 64);
    int cout = og * 16 + (l & 15);
#pragma unroll
    for (int e = 0; e < 8; ++e) {
        int k = c * 32 + ((l >> 4) * 8) + e;
        int tau = k >> 7, ci = k & 127;
        float v = (tau < ntap) ? wsrc[(cout * HD + ci) * ntap + tau] : 0.f;
        dst[tid * 8 + e] = f2bf(v);
    }
}

// ======================= 7x7 conv stack (unchanged, fp32 VALU) =======================
template<int CIN>
__global__ __launch_bounds__(256) void conv7x7_relu(
        const float* __restrict__ x, const float* __restrict__ w,
        const float* __restrict__ bias, float* __restrict__ out) {
    int idx = blockIdx.x * 256 + threadIdx.x;
    int f = idx % F;
    int t = (idx / F) % T;
    int n = idx / (F * T);
    float acc[CF];
#pragma unroll
    for (int co = 0; co < CF; ++co) acc[co] = bias[co];
    for (int ci = 0; ci < CIN; ++ci) {
        const float* xp = x + (n * CIN + ci) * PLANE;
        float xv[49];
#pragma unroll
        for (int dy = 0; dy < 7; ++dy) {
            int tt = t + dy - 3;
            bool tok = (unsigned)tt < (unsigned)T;
#pragma unroll
            for (int dx = 0; dx < 7; ++dx) {
                int ff = f + dx - 3;
                xv[dy * 7 + dx] = (tok && (unsigned)ff < (unsigned)F) ? xp[tt * F + ff] : 0.f;
            }
        }
#pragma unroll
        for (int co = 0; co < CF; ++co) {
            const float* wpc = w + (co * CIN + ci) * 49;
#pragma unroll
            for (int k = 0; k < 49; ++k) acc[co] = fmaf(xv[k], wpc[k], acc[co]);
        }
    }
    float* op = out + n * CF * PLANE + t * F + f;
#pragma unroll
    for (int co = 0; co < CF; ++co) op[co * PLANE] = fmaxf(acc[co], 0.f);
}

// ======================= fused hd (8-dil) + wd0 + relu + pool, MFMA =======================
// WG = one (n,t) row, 512 thr (8 waves). LDS: xT [672 rows][48B] + yT [448 rows][256B] = 146944 B.
// wave: quad = wid&1 (og 0-3 / 4-7), fq = wid>>1 (f-tiles fq,fq+4,...)
__global__ __launch_bounds__(512, 2) void hd_wd0_mfma(
        const float* __restrict__ x1, const u16* __restrict__ WpP,
        const u16* __restrict__ wd0P, const float* __restrict__ bsum,
        const float* __restrict__ bd0, float* __restrict__ zr) {
    extern __shared__ char smem[];
    char* xT = smem;                 // stride 48B, row = f+160, f in [-160,512)
    char* yT = smem + 672 * 48;      // stride 256B, row = f+48,  f in [-48,400), swizzled
    const int n = blockIdx.x / T, t = blockIdx.x % T;
    const int tid = threadIdx.x, l = tid & 63, wid = tid >> 6;
    const int quad = wid & 1, fq = wid >> 1;
    const int g = l >> 4;            // 0..3 (k-group)

    // ---- stage: zero guards + load x row (bf16, transposed) ----
#pragma unroll
    for (int k = 0; k < 4; ++k) {    // xT guards: 320 rows * 6 u64
        int idx = tid + k * 512;
        if (idx < 1920) {
            int row = idx / 6, colb = (idx % 6) * 8;
            int arow = row < 160 ? row : row + 352;
            *(u64*)(xT + arow * 48 + colb) = 0ULL;
        }
    }
#pragma unroll
    for (int k = 0; k < 6; ++k) {    // yT guards: 96 rows * 32 u64
        int idx = tid + k * 512;
        int row = idx >> 5, colb = (idx & 31) * 8;
        int arow = row < 48 ? row : row + 352;
        *(u64*)(yT + arow * 256 + colb) = 0ULL;
    }
    {
        int ci = tid >> 5, fbase = tid & 31;
        const float* xp = x1 + ((size_t)(n * CF + ci) * T + t) * F;
#pragma unroll
        for (int k = 0; k < 11; ++k) {
            int f = fbase + 32 * k;
            *(u16*)(xT + (f + 160) * 48 + ci * 2) = f2bf(xp[f]);
        }
    }
    __syncthreads();

    // ---- phase 1: y = hd conv (M=cout, N=f, K=288) ----
    f32x4 acc[6][4];
#pragma unroll
    for (int og4 = 0; og4 < 4; ++og4) {
        f32x4 b4 = *(const f32x4*)(bsum + (quad * 4 + og4) * 16 + g * 4);
#pragma unroll
        for (int i = 0; i < 6; ++i) acc[i][og4] = b4;
    }
    const int OFFA[9] = {0, -76, -111, -135, -152, 76, 111, 135, 152};
    const int OFFB[9] = {-48, -96, -124, -144, 48, 96, 124, 144, 0};
#pragma unroll
    for (int c = 0; c < 9; ++c) {
        short8 A[4];
#pragma unroll
        for (int og4 = 0; og4 < 4; ++og4)
            A[og4] = *(const short8*)(WpP + ((quad * 4 + og4) * 9 + c) * 512 + l * 8);
        int off = (l >> 5) ? OFFB[c] : OFFA[c];
        int cib = (g & 1) * 16;
#pragma unroll
        for (int i = 0; i < 6; ++i) {
            int ft = fq + 4 * i;
            if (ft < 22) {
                int fr = ft * 16 + (l & 15) + off;
                short8 Bv = *(const short8*)(xT + (fr + 160) * 48 + cib);
#pragma unroll
                for (int og4 = 0; og4 < 4; ++og4) acc[i][og4] = MFMA(A[og4], Bv, acc[i][og4]);
            }
        }
    }
    // write yT (bf16, swizzled)
#pragma unroll
    for (int i = 0; i < 6; ++i) {
        int ft = fq + 4 * i;
        if (ft < 22) {
            int f = ft * 16 + (l & 15);
#pragma unroll
            for (int og4 = 0; og4 < 4; ++og4) {
                int cb = ((quad * 4 + og4) * 16 + g * 4) * 2;
                u64 pk = (u64)f2bf(acc[i][og4][0]) | ((u64)f2bf(acc[i][og4][1]) << 16)
                       | ((u64)f2bf(acc[i][og4][2]) << 32) | ((u64)f2bf(acc[i][og4][3]) << 48);
                *(u64*)(yT + (f + 48) * 256 + (cb ^ ((f & 7) << 4))) = pk;
            }
        }
    }
    __syncthreads();

    // ---- phase 2: wd0 (K=384, taps -48/0/+48) + relu + pool4 ----
#pragma unroll
    for (int og4 = 0; og4 < 4; ++og4) {
        f32x4 b4 = *(const f32x4*)(bd0 + (quad * 4 + og4) * 16 + g * 4);
#pragma unroll
        for (int i = 0; i < 6; ++i) acc[i][og4] = b4;
    }
#pragma unroll
    for (int c = 0; c < 12; ++c) {
        short8 A[4];
#pragma unroll
        for (int og4 = 0; og4 < 4; ++og4)
            A[og4] = *(const short8*)(wd0P + ((quad * 4 + og4) * 12 + c) * 512 + l * 8);
        int off = (c >> 2) * 48 - 48;
        int cib = (c & 3) * 64 + g * 16;
#pragma unroll
        for (int i = 0; i < 6; ++i) {
            int ft = fq + 4 * i;
            if (ft < 22) {
                int fr = ft * 16 + (l & 15) + off;
                short8 Bv = *(const short8*)(yT + (fr + 48) * 256 + (cib ^ ((fr & 7) << 4)));
#pragma unroll
                for (int og4 = 0; og4 < 4; ++og4) acc[i][og4] = MFMA(A[og4], Bv, acc[i][og4]);
            }
        }
    }
#pragma unroll
    for (int i = 0; i < 6; ++i) {
        int ft = fq + 4 * i;
        if (ft < 22) {
#pragma unroll
            for (int og4 = 0; og4 < 4; ++og4) {
                f32x4 v;
#pragma unroll
                for (int r = 0; r < 4; ++r) {
                    float a = fmaxf(acc[i][og4][r], 0.f);
                    a = fmaxf(a, __shfl_xor(a, 1));
                    a = fmaxf(a, __shfl_xor(a, 2));
                    v[r] = a;
                }
                if ((l & 3) == 0) {
                    int fp = (ft * 16 + (l & 15)) >> 2;
                    int cout0 = (quad * 4 + og4) * 16 + g * 4;
                    *(f32x4*)(zr + ((size_t)(n * T + t) * F4 + fp) * HD + cout0) = v;
                }
            }
        }
    }
}

// ======================= wd1: 1x3 dil12, MFMA, LDS-staged =======================
__global__ __launch_bounds__(256) void wd1_mfma(
        const u16* __restrict__ zb, const u16* __restrict__ wP,
        const float* __restrict__ bias, float* __restrict__ out) {
    __shared__ char lds[128 * 256];  // row = f+16, f in [-16,112), swizzled
    const int n = blockIdx.x / T, t = blockIdx.x % T;
    const int tid = threadIdx.x, l = tid & 63, w = tid >> 6;
    const int g = l >> 4;
    {
        int cib = (tid & 15) * 16;
        int fi = tid >> 4;
        const u16* src = zb + (size_t)(n * T + t) * F4 * HD;
#pragma unroll
        for (int k = 0; k < 6; ++k) {
            int f = fi + 16 * k;
            if (f < F4) {
                short8 v = *(const short8*)(src + f * HD + (tid & 15) * 8);
                *(short8*)(lds + (f + 16) * 256 + (cib ^ ((f & 7) << 4))) = v;
            }
        }
#pragma unroll
        for (int k = 0; k < 3; ++k) {   // guards: rows [0,16) + [104,128) = 40 rows * 16 slots
            int idx = tid + k * 256;
            if (idx < 640) {
                int row = idx >> 4, slot = idx & 15;
                int arow = row < 16 ? row : row + 88;
                *(u64*)(lds + arow * 256 + slot * 16) = 0ULL;
                *(u64*)(lds + arow * 256 + slot * 16 + 8) = 0ULL;
            }
        }
    }
    __syncthreads();
    f32x4 acc[6][2];
#pragma unroll
    for (int og2 = 0; og2 < 2; ++og2) {
        f32x4 b4 = *(const f32x4*)(bias + (w * 2 + og2) * 16 + g * 4);
#pragma unroll
        for (int i = 0; i < 6; ++i) acc[i][og2] = b4;
    }
#pragma unroll
    for (int c = 0; c < 12; ++c) {
        short8 A0 = *(const short8*)(wP + ((w * 2 + 0) * 12 + c) * 512 + l * 8);
        short8 A1 = *(const short8*)(wP + ((w * 2 + 1) * 12 + c) * 512 + l * 8);
        int off = (c >> 2) * 12 - 12;
        int cib = (c & 3) * 64 + g * 16;
#pragma unroll
        for (int i = 0; i < 6; ++i) {
            int fr = i * 16 + (l & 15) + off;
            short8 Bv = *(const short8*)(lds + (fr + 16) * 256 + (cib ^ ((fr & 7) << 4)));
            acc[i][0] = MFMA(A0, Bv, acc[i][0]);
            acc[i][1] = MFMA(A1, Bv, acc[i][1]);
        }
    }
#pragma unroll
    for (int i = 0; i < 6; ++i) {
        int f = i * 16 + (l & 15);
        if (f < F4) {
#pragma unroll
            for (int og2 = 0; og2 < 2; ++og2) {
                int cout0 = (w * 2 + og2) * 16 + g * 4;
                f32x4 v;
#pragma unroll
                for (int r = 0; r < 4; ++r) v[r] = fmaxf(acc[i][og2][r], 0.f);
                *(f32x4*)(out + ((size_t)(n * T + t) * F4 + f) * HD + cout0) = v;
            }
        }
    }
}

// ======================= wd2/3/4: 5x1 time conv, MFMA, direct-global B =======================
template<bool NCHW_OUT>
__global__ __launch_bounds__(256) void wd5_mfma(
        const u16* __restrict__ zb, const u16* __restrict__ wP,
        const float* __restrict__ bias, float* __restrict__ out) {
    const int n = blockIdx.x / T, t = blockIdx.x % T;
    const int tid = threadIdx.x, l = tid & 63, w = tid >> 6;
    const int g = l >> 4;
    f32x4 acc[6][2];
#pragma unroll
    for (int og2 = 0; og2 < 2; ++og2) {
        f32x4 b4 = *(const f32x4*)(bias + (w * 2 + og2) * 16 + g * 4);
#pragma unroll
        for (int i = 0; i < 6; ++i) acc[i][og2] = b4;
    }
#pragma unroll
    for (int c = 0; c < 20; ++c) {
        int trow = t + (c >> 2) - 2;
        if ((unsigned)trow < (unsigned)T) {
            short8 A0 = *(const short8*)(wP + ((w * 2 + 0) * 20 + c) * 512 + l * 8);
            short8 A1 = *(const short8*)(wP + ((w * 2 + 1) * 20 + c) * 512 + l * 8);
            int cio = (c & 3) * 32 + g * 8;
            const u16* brow = zb + (size_t)(n * T + trow) * F4 * HD;
#pragma unroll
            for (int i = 0; i < 6; ++i) {
                int f = i * 16 + (l & 15);
                short8 Bv = *(const short8*)(brow + f * HD + cio);
                acc[i][0] = MFMA(A0, Bv, acc[i][0]);
                acc[i][1] = MFMA(A1, Bv, acc[i][1]);
            }
        }
    }
#pragma unroll
    for (int i = 0; i < 6; ++i) {
        int f = i * 16 + (l & 15);
        if (f < F4) {
#pragma unroll
            for (int og2 = 0; og2 < 2; ++og2) {
                int cout0 = (w * 2 + og2) * 16 + g * 4;
                if (NCHW_OUT) {
#pragma unroll
                    for (int r = 0; r < 4; ++r)
                        out[((size_t)(n * HD + cout0 + r) * T + t) * F4 + f] =
                            fmaxf(acc[i][og2][r], 0.f);
                } else {
                    f32x4 v;
#pragma unroll
                    for (int r = 0; r < 4; ++r) v[r] = fmaxf(acc[i][og2][r], 0.f);
                    *(f32x4*)(out + ((size_t)(n * T + t) * F4 + f) * HD + cout0) = v;
                }
            }
        }
    }
}

// ======================= instance norm, NHWC (fp32 in -> stats -> bf16 out) =======================
__global__ __launch_bounds__(256) void stats_nhwc(const float* __restrict__ zr,
                                                  float* __restrict__ part) {
    int b = blockIdx.x;                  // 256: n = b>>6, chunk = b&63 (8 rows each)
    int n = b >> 6, ch = b & 63;
    int c4 = (threadIdx.x & 31) * 4;
    int rg = threadIdx.x >> 5;           // 0..7
    int row = ch * 8 + rg;
    const float* rp = zr + ((size_t)(n * T + row) * F4) * HD + c4;
    float s0 = 0, s1 = 0, s2 = 0, s3 = 0, q0 = 0, q1 = 0, q2 = 0, q3 = 0;
    for (int f = 0; f < F4; ++f) {
        float4 v = *(const float4*)(rp + f * HD);
        s0 += v.x; s1 += v.y; s2 += v.z; s3 += v.w;
        q0 += v.x * v.x; q1 += v.y * v.y; q2 += v.z * v.z; q3 += v.w * v.w;
    }
    __shared__ float red[8][32][8];
    float* rr = red[rg][threadIdx.x & 31];
    rr[0] = s0; rr[1] = s1; rr[2] = s2; rr[3] = s3;
    rr[4] = q0; rr[5] = q1; rr[6] = q2; rr[7] = q3;
    __syncthreads();
    if (threadIdx.x < 32) {
        float acc[8] = {0, 0, 0, 0, 0, 0, 0, 0};
        for (int j = 0; j < 8; ++j)
            for (int e = 0; e < 8; ++e) acc[e] += red[j][threadIdx.x][e];
        for (int e = 0; e < 4; ++e) {
            part[((size_t)b * HD + threadIdx.x * 4 + e) * 2 + 0] = acc[e];
            part[((size_t)b * HD + threadIdx.x * 4 + e) * 2 + 1] = acc[4 + e];
        }
    }
}

__global__ void finalize_nhwc(const float* __restrict__ part, float* __restrict__ mean,
                              float* __restrict__ rstd) {
    int p = blockIdx.x * blockDim.x + threadIdx.x;   // 512: n = p>>7, c = p&127
    if (p >= B * HD) return;
    int n = p >> 7, c = p & 127;
    float s = 0, q = 0;
    for (int ch = 0; ch < 64; ++ch) {
        s += part[((size_t)(n * 64 + ch) * HD + c) * 2 + 0];
        q += part[((size_t)(n * 64 + ch) * HD + c) * 2 + 1];
    }
    float m = s / (float)PLANE4;
    mean[p] = m;
    rstd[p] = rsqrtf(q / (float)PLANE4 - m * m + 1e-5f);
}

__global__ __launch_bounds__(256) void apply_nhwc(const float* __restrict__ zr,
                                                  u16* __restrict__ zb,
                                                  const float* __restrict__ mean,
                                                  const float* __restrict__ rstd) {
    int i4 = blockIdx.x * 256 + threadIdx.x;         // < 5,767,168
    int c4 = (i4 & 31) * 4;
    int n = i4 / (T * F4 * 32);
    float4 v = *(const float4*)(zr + (size_t)i4 * 4);
    float4 m = *(const float4*)(mean + n * HD + c4);
    float4 r = *(const float4*)(rstd + n * HD + c4);
    u64 pk = (u64)f2bf((v.x - m.x) * r.x) | ((u64)f2bf((v.y - m.y) * r.y) << 16)
           | ((u64)f2bf((v.z - m.z) * r.z) << 32) | ((u64)f2bf((v.w - m.w) * r.w) << 48);
    *(u64*)(zb + (size_t)i4 * 4) = pk;
}

// ======================= instance norm, NCHW (unchanged) =======================
__global__ __launch_bounds__(256) void inorm_stats(const float* __restrict__ x,
                                                   float* __restrict__ part,
                                                   int plane, int nchunks) {
    int p = blockIdx.x / nchunks, c = blockIdx.x % nchunks;
    int len = plane / nchunks;
    const float4* xp = (const float4*)(x + (size_t)p * plane + (size_t)c * len);
    int n4 = len / 4;
    float s = 0.f, q = 0.f;
    for (int i = threadIdx.x; i < n4; i += 256) {
        float4 v = xp[i];
        s += v.x + v.y + v.z + v.w;
        q += v.x * v.x + v.y * v.y + v.z * v.z + v.w * v.w;
    }
#pragma unroll
    for (int off = 32; off > 0; off >>= 1) {
        s += __shfl_down(s, off);
        q += __shfl_down(q, off);
    }
    __shared__ float ss[4], qq[4];
    int wid = threadIdx.x >> 6;
    if ((threadIdx.x & 63) == 0) { ss[wid] = s; qq[wid] = q; }
    __syncthreads();
    if (threadIdx.x == 0) {
        part[blockIdx.x * 2]     = ss[0] + ss[1] + ss[2] + ss[3];
        part[blockIdx.x * 2 + 1] = qq[0] + qq[1] + qq[2] + qq[3];
    }
}

__global__ void inorm_finalize(const float* __restrict__ part, float* __restrict__ mean,
                               float* __restrict__ rstd, int nplanes, int nchunks,
                               float inv_plane) {
    int p = blockIdx.x * blockDim.x + threadIdx.x;
    if (p >= nplanes) return;
    float s = 0.f, q = 0.f;
    for (int c = 0; c < nchunks; ++c) {
        s += part[(p * nchunks + c) * 2];
        q += part[(p * nchunks + c) * 2 + 1];
    }
    float m = s * inv_plane;
    mean[p] = m;
    rstd[p] = rsqrtf(q * inv_plane - m * m + 1e-5f);
}

template<int PSIZE>
__global__ __launch_bounds__(256) void inorm_apply(const float* __restrict__ in,
                                                   float* __restrict__ out,
                                                   const float* __restrict__ mean,
                                                   const float* __restrict__ rstd) {
    int i4 = blockIdx.x * 256 + threadIdx.x;
    int p = (i4 * 4) / PSIZE;
    float m = mean[p], r = rstd[p];
    float4 v = ((const float4*)in)[i4];
    v.x = (v.x - m) * r; v.y = (v.y - m) * r; v.z = (v.z - m) * r; v.w = (v.w - m) * r;
    ((float4*)out)[i4] = v;
}

// ======================= launcher =======================
extern "C" void kernel_launch(void* const* d_in, const int* in_sizes, int n_in,
                              void* d_out, int out_size, void* d_ws, size_t ws_size,
                              hipStream_t stream) {
    (void)in_sizes; (void)n_in; (void)out_size; (void)ws_size;
    const float* cqt  = (const float*)d_in[0];
    const float* w0   = (const float*)d_in[1];  const float* b0  = (const float*)d_in[2];
    const float* w1   = (const float*)d_in[3];  const float* b1  = (const float*)d_in[4];
    const float* w2   = (const float*)d_in[5];  const float* b2  = (const float*)d_in[6];
    const float* w_hd = (const float*)d_in[7];  const float* bhd = (const float*)d_in[8];
    const float* wd0  = (const float*)d_in[9];  const float* bd0 = (const float*)d_in[10];
    const float* wd1  = (const float*)d_in[11]; const float* bd1 = (const float*)d_in[12];
    const float* wd2  = (const float*)d_in[13]; const float* bd2 = (const float*)d_in[14];
    const float* wd3  = (const float*)d_in[15]; const float* bd3 = (const float*)d_in[16];
    const float* wd4  = (const float*)d_in[17]; const float* bd4 = (const float*)d_in[18];
    float* zr = (float*)d_out;                      // fp32 pre-norm scratch == output buffer

    // workspace (~93.3 MB)
    float* x1   = (float*)d_ws;                               // 11,534,336 f
    u16*   zb16 = (u16*)(x1 + (size_t)B * CF * PLANE);        // 23,068,672 + 2048 slack u16
    float* x2   = (float*)zb16;                               // alias (dead before zb16 written)
    u16*   packW = zb16 + (size_t)23068672 + 2048;
    u16*   WpP  = packW;                                      // 8*9*64*8   = 36,864
    u16*   wd0P = WpP  + 36864;                               // 8*12*64*8  = 49,152
    u16*   wd1P = wd0P + 49152;
    u16*   wd2P = wd1P + 49152;                               // 8*20*64*8  = 81,920
    u16*   wd3P = wd2P + 81920;
    u16*   wd4P = wd3P + 81920;
    float* bsum = (float*)(wd4P + 81920);                     // 128
    float* part = bsum + 128;                                 // 65,536
    float* meanb = part + 65536;                              // 512
    float* rstdb = meanb + 512;                               // 512

    auto norm_big = [&](float* bin, float* bout) {
        inorm_stats<<<64 * 8, 256, 0, stream>>>(bin, part, PLANE, 8);
        inorm_finalize<<<1, 64, 0, stream>>>(part, meanb, rstdb, 64, 8, 1.f / PLANE);
        inorm_apply<PLANE><<<64 * PLANE / 4 / 256, 256, 0, stream>>>(bin, bout, meanb, rstdb);
    };
    auto norm_nhwc = [&]() {   // zr (d_out) -> zb16
        stats_nhwc<<<256, 256, 0, stream>>>(zr, part);
        finalize_nhwc<<<2, 256, 0, stream>>>(part, meanb, rstdb);
        apply_nhwc<<<B * T * F4 * HD / 4 / 256, 256, 0, stream>>>(zr, zb16, meanb, rstdb);
    };

    // weight packing
    prep_hd_pack<<<18, 256, 0, stream>>>(w_hd, bhd, WpP, bsum);
    pack_wd<<<24, 256, 0, stream>>>(wd0, wd0P, 3, 12);
    pack_wd<<<24, 256, 0, stream>>>(wd1, wd1P, 3, 12);
    pack_wd<<<40, 256, 0, stream>>>(wd2, wd2P, 5, 20);
    pack_wd<<<40, 256, 0, stream>>>(wd3, wd3P, 5, 20);
    pack_wd<<<40, 256, 0, stream>>>(wd4, wd4P, 5, 20);

    // 7x7 conv stack (NCHW fp32)
    conv7x7_relu<1><<<B * T * F / 256, 256, 0, stream>>>(cqt, w0, b0, x1);
    norm_big(x1, x1);
    conv7x7_relu<16><<<B * T * F / 256, 256, 0, stream>>>(x1, w1, b1, x2);
    norm_big(x2, x2);
    conv7x7_relu<16><<<B * T * F / 256, 256, 0, stream>>>(x2, w2, b2, x1);
    norm_big(x1, x1);

    // fused hd + wd0 + relu + pool (MFMA) -> zr (NHWC fp32)
    hipFuncSetAttribute((const void*)hd_wd0_mfma,
                        hipFuncAttributeMaxDynamicSharedMemorySize, 147456);
    hd_wd0_mfma<<<B * T, 512, 146944, stream>>>(x1, WpP, wd0P, bsum, bd0, zr);
    norm_nhwc();

    wd1_mfma<<<B * T, 256, 0, stream>>>(zb16, wd1P, bd1, zr);
    norm_nhwc();
    wd5_mfma<false><<<B * T, 256, 0, stream>>>(zb16, wd2P, bd2, zr);
    norm_nhwc();
    wd5_mfma<false><<<B * T, 256, 0, stream>>>(zb16, wd3P, bd3, zr);
    norm_nhwc();
    wd5_mfma<true><<<B * T, 256, 0, stream>>>(zb16, wd4P, bd4, zr);  // NCHW out

    // final instance norm on NCHW output, in place
    inorm_stats<<<512 * 4, 256, 0, stream>>>(zr, part, PLANE4, 4);
    inorm_finalize<<<1, 512, 0, stream>>>(part, meanb, rstdb, 512, 4, 1.f / PLANE4);
    inorm_apply<PLANE4><<<512 * PLANE4 / 4 / 256, 256, 0, stream>>>(zr, zr, meanb, rstdb);
}

// Round 7
// 1191.733 us; speedup vs baseline: 10.7094x; 2.5543x over previous
//
#include <hip/hip_runtime.h>
#include <hip/hip_bf16.h>

constexpr int B = 4, T = 512, F = 352, CF = 16, HD = 128, F4 = 88;
constexpr int PLANE  = T * F;    // 180224
constexpr int PLANE4 = T * F4;   // 45056
constexpr int NDIL = 8;
constexpr int FP = 360;          // padded f width for xb (f' = f+3, cols 355..359 zero)

typedef __attribute__((ext_vector_type(8))) short short8;
typedef __attribute__((ext_vector_type(8))) _Float16 half8;
typedef __attribute__((ext_vector_type(4))) float f32x4;
typedef unsigned short u16;
typedef unsigned long long u64;

#define MFMA(a, b, c)   __builtin_amdgcn_mfma_f32_16x16x32_bf16(a, b, c, 0, 0, 0)
#define MFMA16(a, b, c) __builtin_amdgcn_mfma_f32_16x16x32_f16(a, b, c, 0, 0, 0)

__device__ inline u16 f2bf(float x) {
    unsigned u = __float_as_uint(x);
    return (u16)((u + 0x7fffu + ((u >> 16) & 1u)) >> 16);
}
__device__ inline u16 f2h(float x) {
    _Float16 h = (_Float16)x;
    u16 r; __builtin_memcpy(&r, &h, 2);
    return r;
}

// ======================= weight packing =======================
// A-frag: value(chunk c, lane l, e) = W[m = l&15][k = c*32 + (l>>4)*8 + e]
__global__ void prep_hd_pack(const float* __restrict__ w_hd, const float* __restrict__ b_hd,
                             u16* __restrict__ WpP, float* __restrict__ bsum) {
    int tid = blockIdx.x * 256 + threadIdx.x;
    if (tid < HD) {
        float s = 0.f;
        for (int d = 0; d < NDIL; ++d) s += b_hd[d * HD + tid];
        bsum[tid] = s;
    }
    if (tid >= 8 * 9 * 64) return;
    int l = tid & 63, c = (tid >> 6) % 9, og = tid / (9 * 64);
    int cout = og * 16 + (l & 15);
#pragma unroll
    for (int e = 0; e < 8; ++e) {
        int k = c * 32 + ((l >> 4) * 8) + e;
        int tau = k >> 4, ci = k & 15;
        float v = 0.f;
        if (tau == 0) {
            for (int d = 0; d < NDIL; ++d) v += w_hd[((d * HD + cout) * CF + ci) * 3 + 1];
        } else if (tau <= 8) {
            v = w_hd[(((tau - 1) * HD + cout) * CF + ci) * 3 + 0];
        } else if (tau <= 16) {
            v = w_hd[(((tau - 9) * HD + cout) * CF + ci) * 3 + 2];
        }
        WpP[tid * 8 + e] = f2bf(v);
    }
}

// wd convs: k -> tau = k>>7, ci = k&127; src layout [cout][ci][ntap]
__global__ void pack_wd(const float* __restrict__ wsrc, u16* __restrict__ dst,
                        int ntap, int nch) {
    int tid = blockIdx.x * 256 + threadIdx.x;
    if (tid >= 8 * nch * 64) return;
    int l = tid & 63, c = (tid >> 6) % nch, og = tid / (nch * 64);
    int cout = og * 16 + (l & 15);
#pragma unroll
    for (int e = 0; e < 8; ++e) {
        int k = c * 32 + ((l >> 4) * 8) + e;
        int tau = k >> 7, ci = k & 127;
        float v = (tau < ntap) ? wsrc[(cout * HD + ci) * ntap + tau] : 0.f;
        dst[tid * 8 + e] = f2bf(v);
    }
}

// conv7x7 weights (16,16,7,7) -> fp16 A-frags [28][64][8]; tau' = dy*8+dx (dx=7 zero)
__global__ void pack_c7(const float* __restrict__ wsrc, u16* __restrict__ dst) {
    int tid = blockIdx.x * 256 + threadIdx.x;
    if (tid >= 28 * 64) return;
    int l = tid & 63, c = tid >> 6;
    int cout = l & 15, g = l >> 4;
#pragma unroll
    for (int e = 0; e < 8; ++e) {
        int k = c * 32 + g * 8 + e;
        int taup = k >> 4, ci = k & 15;
        int dy = taup >> 3, dx = taup & 7;
        float v = (dx < 7) ? wsrc[((cout * CF + ci) * 7 + dy) * 7 + dx] : 0.f;
        dst[tid * 8 + e] = f2h(v);
    }
}

// ======================= conv0 (CIN=1, fp32 VALU) =======================
__global__ __launch_bounds__(256) void conv7x7_c1(
        const float* __restrict__ x, const float* __restrict__ w,
        const float* __restrict__ bias, float* __restrict__ out) {
    int idx = blockIdx.x * 256 + threadIdx.x;
    int f = idx % F;
    int t = (idx / F) % T;
    int n = idx / (F * T);
    float acc[CF];
#pragma unroll
    for (int co = 0; co < CF; ++co) acc[co] = bias[co];
    const float* xp = x + n * PLANE;
    float xv[49];
#pragma unroll
    for (int dy = 0; dy < 7; ++dy) {
        int tt = t + dy - 3;
        bool tok = (unsigned)tt < (unsigned)T;
#pragma unroll
        for (int dx = 0; dx < 7; ++dx) {
            int ff = f + dx - 3;
            xv[dy * 7 + dx] = (tok && (unsigned)ff < (unsigned)F) ? xp[tt * F + ff] : 0.f;
        }
    }
#pragma unroll
    for (int co = 0; co < CF; ++co) {
        const float* wpc = w + co * 49;
#pragma unroll
        for (int k = 0; k < 49; ++k) acc[co] = fmaf(xv[k], wpc[k], acc[co]);
    }
    float* op = out + n * CF * PLANE + t * F + f;
#pragma unroll
    for (int co = 0; co < CF; ++co) op[co * PLANE] = fmaxf(acc[co], 0.f);
}

// ======================= conv1/conv2: 7x7 MFMA fp16, direct-global B =======================
// WG = (n,t) row, 256 thr (4 waves). B from padded fp16 NHWC xb[n][t][FP][16].
__global__ __launch_bounds__(256) void conv7_mfma(
        const u16* __restrict__ xb, const u16* __restrict__ wP,
        const float* __restrict__ bias, float* __restrict__ out) {  // out NCHW fp32 +relu
    const int n = blockIdx.x / T, t = blockIdx.x % T;
    const int l = threadIdx.x & 63, w = threadIdx.x >> 6;
    const int g = l >> 4;
    f32x4 acc[6];
    {
        f32x4 b4 = *(const f32x4*)(bias + g * 4);
#pragma unroll
        for (int i = 0; i < 6; ++i) acc[i] = b4;
    }
    for (int c = 0; c < 28; ++c) {
        int trow = t + (c >> 2) - 3;
        if ((unsigned)trow >= (unsigned)T) continue;        // wave-uniform skip (x=0 pad)
        half8 A = *(const half8*)(wP + c * 512 + l * 8);
        int dx = 2 * (c & 3) + (g >> 1);
        const u16* brow = xb + (size_t)(n * T + trow) * FP * 16;
#pragma unroll
        for (int i = 0; i < 6; ++i) {
            int ft = w + 4 * i;
            if (ft < 22) {
                int fcol = ft * 16 + (l & 15) + dx;         // = f_center + dx (f' = f+3 layout)
                half8 Bv = *(const half8*)(brow + fcol * 16 + (g & 1) * 8);
                acc[i] = MFMA16(A, Bv, acc[i]);
            }
        }
    }
#pragma unroll
    for (int i = 0; i < 6; ++i) {
        int ft = w + 4 * i;
        if (ft < 22) {
            int f = ft * 16 + (l & 15);
#pragma unroll
            for (int r = 0; r < 4; ++r)
                out[((size_t)(n * CF + g * 4 + r) * T + t) * F + f] = fmaxf(acc[i][r], 0.f);
        }
    }
}

// ======================= norm-apply for cnn stack =======================
// MODE 0: write padded fp16 NHWC xb ; MODE 1: write fp32 NCHW (for hd input)
template<int MODE>
__global__ __launch_bounds__(256) void apply_xb(
        const float* __restrict__ xin,      // NCHW fp32 (pre-norm)
        u16* __restrict__ xb, float* __restrict__ xf32,
        const float* __restrict__ mean, const float* __restrict__ rstd) {
    const int n = blockIdx.x / T, t = blockIdx.x % T;
    const int tid = threadIdx.x;
    float m[CF], r[CF];
#pragma unroll
    for (int ci = 0; ci < CF; ++ci) {
        m[ci] = mean[n * CF + ci];
        r[ci] = rstd[n * CF + ci];
    }
    if (MODE == 0 && tid < 32) {            // zero guard cols {0,1,2,355..359}
        int colIdx = tid >> 2;
        int col = colIdx < 3 ? colIdx : 352 + colIdx;
        *(u64*)(xb + ((size_t)(n * T + t) * FP + col) * 16 + (tid & 3) * 4) = 0ULL;
    }
    for (int f = tid; f < F; f += 256) {
        const float* xp = xin + ((size_t)n * CF * T + t) * F + f;
        if (MODE == 0) {
            u64 pk[4];
            u16* ph = (u16*)pk;
#pragma unroll
            for (int ci = 0; ci < CF; ++ci)
                ph[ci] = f2h((xp[ci * PLANE] - m[ci]) * r[ci]);
            u64* dst = (u64*)(xb + ((size_t)(n * T + t) * FP + f + 3) * 16);
#pragma unroll
            for (int q = 0; q < 4; ++q) dst[q] = pk[q];
        } else {
            float* op = xf32 + ((size_t)n * CF * T + t) * F + f;
#pragma unroll
            for (int ci = 0; ci < CF; ++ci)
                op[ci * PLANE] = (xp[ci * PLANE] - m[ci]) * r[ci];
        }
    }
}

// ======================= fused hd (8-dil) + wd0 + relu + pool, MFMA =======================
__global__ __launch_bounds__(512, 2) void hd_wd0_mfma(
        const float* __restrict__ x1, const u16* __restrict__ WpP,
        const u16* __restrict__ wd0P, const float* __restrict__ bsum,
        const float* __restrict__ bd0, float* __restrict__ zr) {
    extern __shared__ char smem[];
    char* xT = smem;                 // stride 48B, row = f+160, f in [-160,512)
    char* yT = smem + 672 * 48;      // stride 256B, row = f+48,  f in [-48,400), swizzled
    const int n = blockIdx.x / T, t = blockIdx.x % T;
    const int tid = threadIdx.x, l = tid & 63, wid = tid >> 6;
    const int quad = wid & 1, fq = wid >> 1;
    const int g = l >> 4;

#pragma unroll
    for (int k = 0; k < 4; ++k) {
        int idx = tid + k * 512;
        if (idx < 1920) {
            int row = idx / 6, colb = (idx % 6) * 8;
            int arow = row < 160 ? row : row + 352;
            *(u64*)(xT + arow * 48 + colb) = 0ULL;
        }
    }
#pragma unroll
    for (int k = 0; k < 6; ++k) {
        int idx = tid + k * 512;
        int row = idx >> 5, colb = (idx & 31) * 8;
        int arow = row < 48 ? row : row + 352;
        *(u64*)(yT + arow * 256 + colb) = 0ULL;
    }
    {
        int ci = tid >> 5, fbase = tid & 31;
        const float* xp = x1 + ((size_t)(n * CF + ci) * T + t) * F;
#pragma unroll
        for (int k = 0; k < 11; ++k) {
            int f = fbase + 32 * k;
            *(u16*)(xT + (f + 160) * 48 + ci * 2) = f2bf(xp[f]);
        }
    }
    __syncthreads();

    f32x4 acc[6][4];
#pragma unroll
    for (int og4 = 0; og4 < 4; ++og4) {
        f32x4 b4 = *(const f32x4*)(bsum + (quad * 4 + og4) * 16 + g * 4);
#pragma unroll
        for (int i = 0; i < 6; ++i) acc[i][og4] = b4;
    }
    const int OFFA[9] = {0, -76, -111, -135, -152, 76, 111, 135, 152};
    const int OFFB[9] = {-48, -96, -124, -144, 48, 96, 124, 144, 0};
#pragma unroll
    for (int c = 0; c < 9; ++c) {
        short8 A[4];
#pragma unroll
        for (int og4 = 0; og4 < 4; ++og4)
            A[og4] = *(const short8*)(WpP + ((quad * 4 + og4) * 9 + c) * 512 + l * 8);
        int off = (l >> 5) ? OFFB[c] : OFFA[c];
        int cib = (g & 1) * 16;
#pragma unroll
        for (int i = 0; i < 6; ++i) {
            int ft = fq + 4 * i;
            if (ft < 22) {
                int fr = ft * 16 + (l & 15) + off;
                short8 Bv = *(const short8*)(xT + (fr + 160) * 48 + cib);
#pragma unroll
                for (int og4 = 0; og4 < 4; ++og4) acc[i][og4] = MFMA(A[og4], Bv, acc[i][og4]);
            }
        }
    }
#pragma unroll
    for (int i = 0; i < 6; ++i) {
        int ft = fq + 4 * i;
        if (ft < 22) {
            int f = ft * 16 + (l & 15);
#pragma unroll
            for (int og4 = 0; og4 < 4; ++og4) {
                int cb = ((quad * 4 + og4) * 16 + g * 4) * 2;
                u64 pk = (u64)f2bf(acc[i][og4][0]) | ((u64)f2bf(acc[i][og4][1]) << 16)
                       | ((u64)f2bf(acc[i][og4][2]) << 32) | ((u64)f2bf(acc[i][og4][3]) << 48);
                *(u64*)(yT + (f + 48) * 256 + (cb ^ ((f & 7) << 4))) = pk;
            }
        }
    }
    __syncthreads();

#pragma unroll
    for (int og4 = 0; og4 < 4; ++og4) {
        f32x4 b4 = *(const f32x4*)(bd0 + (quad * 4 + og4) * 16 + g * 4);
#pragma unroll
        for (int i = 0; i < 6; ++i) acc[i][og4] = b4;
    }
#pragma unroll
    for (int c = 0; c < 12; ++c) {
        short8 A[4];
#pragma unroll
        for (int og4 = 0; og4 < 4; ++og4)
            A[og4] = *(const short8*)(wd0P + ((quad * 4 + og4) * 12 + c) * 512 + l * 8);
        int off = (c >> 2) * 48 - 48;
        int cib = (c & 3) * 64 + g * 16;
#pragma unroll
        for (int i = 0; i < 6; ++i) {
            int ft = fq + 4 * i;
            if (ft < 22) {
                int fr = ft * 16 + (l & 15) + off;
                short8 Bv = *(const short8*)(yT + (fr + 48) * 256 + (cib ^ ((fr & 7) << 4)));
#pragma unroll
                for (int og4 = 0; og4 < 4; ++og4) acc[i][og4] = MFMA(A[og4], Bv, acc[i][og4]);
            }
        }
    }
#pragma unroll
    for (int i = 0; i < 6; ++i) {
        int ft = fq + 4 * i;
        if (ft < 22) {
#pragma unroll
            for (int og4 = 0; og4 < 4; ++og4) {
                f32x4 v;
#pragma unroll
                for (int r = 0; r < 4; ++r) {
                    float a = fmaxf(acc[i][og4][r], 0.f);
                    a = fmaxf(a, __shfl_xor(a, 1));
                    a = fmaxf(a, __shfl_xor(a, 2));
                    v[r] = a;
                }
                if ((l & 3) == 0) {
                    int fp = (ft * 16 + (l & 15)) >> 2;
                    int cout0 = (quad * 4 + og4) * 16 + g * 4;
                    *(f32x4*)(zr + ((size_t)(n * T + t) * F4 + fp) * HD + cout0) = v;
                }
            }
        }
    }
}

// ======================= wd1: 1x3 dil12, MFMA, LDS-staged =======================
__global__ __launch_bounds__(256) void wd1_mfma(
        const u16* __restrict__ zb, const u16* __restrict__ wP,
        const float* __restrict__ bias, float* __restrict__ out) {
    __shared__ char lds[128 * 256];
    const int n = blockIdx.x / T, t = blockIdx.x % T;
    const int tid = threadIdx.x, l = tid & 63, w = tid >> 6;
    const int g = l >> 4;
    {
        int cib = (tid & 15) * 16;
        int fi = tid >> 4;
        const u16* src = zb + (size_t)(n * T + t) * F4 * HD;
#pragma unroll
        for (int k = 0; k < 6; ++k) {
            int f = fi + 16 * k;
            if (f < F4) {
                short8 v = *(const short8*)(src + f * HD + (tid & 15) * 8);
                *(short8*)(lds + (f + 16) * 256 + (cib ^ ((f & 7) << 4))) = v;
            }
        }
#pragma unroll
        for (int k = 0; k < 3; ++k) {
            int idx = tid + k * 256;
            if (idx < 640) {
                int row = idx >> 4, slot = idx & 15;
                int arow = row < 16 ? row : row + 88;
                *(u64*)(lds + arow * 256 + slot * 16) = 0ULL;
                *(u64*)(lds + arow * 256 + slot * 16 + 8) = 0ULL;
            }
        }
    }
    __syncthreads();
    f32x4 acc[6][2];
#pragma unroll
    for (int og2 = 0; og2 < 2; ++og2) {
        f32x4 b4 = *(const f32x4*)(bias + (w * 2 + og2) * 16 + g * 4);
#pragma unroll
        for (int i = 0; i < 6; ++i) acc[i][og2] = b4;
    }
#pragma unroll
    for (int c = 0; c < 12; ++c) {
        short8 A0 = *(const short8*)(wP + ((w * 2 + 0) * 12 + c) * 512 + l * 8);
        short8 A1 = *(const short8*)(wP + ((w * 2 + 1) * 12 + c) * 512 + l * 8);
        int off = (c >> 2) * 12 - 12;
        int cib = (c & 3) * 64 + g * 16;
#pragma unroll
        for (int i = 0; i < 6; ++i) {
            int fr = i * 16 + (l & 15) + off;
            short8 Bv = *(const short8*)(lds + (fr + 16) * 256 + (cib ^ ((fr & 7) << 4)));
            acc[i][0] = MFMA(A0, Bv, acc[i][0]);
            acc[i][1] = MFMA(A1, Bv, acc[i][1]);
        }
    }
#pragma unroll
    for (int i = 0; i < 6; ++i) {
        int f = i * 16 + (l & 15);
        if (f < F4) {
#pragma unroll
            for (int og2 = 0; og2 < 2; ++og2) {
                int cout0 = (w * 2 + og2) * 16 + g * 4;
                f32x4 v;
#pragma unroll
                for (int r = 0; r < 4; ++r) v[r] = fmaxf(acc[i][og2][r], 0.f);
                *(f32x4*)(out + ((size_t)(n * T + t) * F4 + f) * HD + cout0) = v;
            }
        }
    }
}

// ======================= wd2/3/4: 5x1 time conv, MFMA, direct-global B =======================
template<bool NCHW_OUT>
__global__ __launch_bounds__(256) void wd5_mfma(
        const u16* __restrict__ zb, const u16* __restrict__ wP,
        const float* __restrict__ bias, float* __restrict__ out) {
    const int n = blockIdx.x / T, t = blockIdx.x % T;
    const int tid = threadIdx.x, l = tid & 63, w = tid >> 6;
    const int g = l >> 4;
    f32x4 acc[6][2];
#pragma unroll
    for (int og2 = 0; og2 < 2; ++og2) {
        f32x4 b4 = *(const f32x4*)(bias + (w * 2 + og2) * 16 + g * 4);
#pragma unroll
        for (int i = 0; i < 6; ++i) acc[i][og2] = b4;
    }
#pragma unroll
    for (int c = 0; c < 20; ++c) {
        int trow = t + (c >> 2) - 2;
        if ((unsigned)trow < (unsigned)T) {
            short8 A0 = *(const short8*)(wP + ((w * 2 + 0) * 20 + c) * 512 + l * 8);
            short8 A1 = *(const short8*)(wP + ((w * 2 + 1) * 20 + c) * 512 + l * 8);
            int cio = (c & 3) * 32 + g * 8;
            const u16* brow = zb + (size_t)(n * T + trow) * F4 * HD;
#pragma unroll
            for (int i = 0; i < 6; ++i) {
                int f = i * 16 + (l & 15);
                short8 Bv = *(const short8*)(brow + f * HD + cio);
                acc[i][0] = MFMA(A0, Bv, acc[i][0]);
                acc[i][1] = MFMA(A1, Bv, acc[i][1]);
            }
        }
    }
#pragma unroll
    for (int i = 0; i < 6; ++i) {
        int f = i * 16 + (l & 15);
        if (f < F4) {
#pragma unroll
            for (int og2 = 0; og2 < 2; ++og2) {
                int cout0 = (w * 2 + og2) * 16 + g * 4;
                if (NCHW_OUT) {
#pragma unroll
                    for (int r = 0; r < 4; ++r)
                        out[((size_t)(n * HD + cout0 + r) * T + t) * F4 + f] =
                            fmaxf(acc[i][og2][r], 0.f);
                } else {
                    f32x4 v;
#pragma unroll
                    for (int r = 0; r < 4; ++r) v[r] = fmaxf(acc[i][og2][r], 0.f);
                    *(f32x4*)(out + ((size_t)(n * T + t) * F4 + f) * HD + cout0) = v;
                }
            }
        }
    }
}

// ======================= instance norm, NHWC =======================
__global__ __launch_bounds__(256) void stats_nhwc(const float* __restrict__ zr,
                                                  float* __restrict__ part) {
    int b = blockIdx.x;
    int n = b >> 6, ch = b & 63;
    int c4 = (threadIdx.x & 31) * 4;
    int rg = threadIdx.x >> 5;
    int row = ch * 8 + rg;
    const float* rp = zr + ((size_t)(n * T + row) * F4) * HD + c4;
    float s0 = 0, s1 = 0, s2 = 0, s3 = 0, q0 = 0, q1 = 0, q2 = 0, q3 = 0;
    for (int f = 0; f < F4; ++f) {
        float4 v = *(const float4*)(rp + f * HD);
        s0 += v.x; s1 += v.y; s2 += v.z; s3 += v.w;
        q0 += v.x * v.x; q1 += v.y * v.y; q2 += v.z * v.z; q3 += v.w * v.w;
    }
    __shared__ float red[8][32][8];
    float* rr = red[rg][threadIdx.x & 31];
    rr[0] = s0; rr[1] = s1; rr[2] = s2; rr[3] = s3;
    rr[4] = q0; rr[5] = q1; rr[6] = q2; rr[7] = q3;
    __syncthreads();
    if (threadIdx.x < 32) {
        float acc[8] = {0, 0, 0, 0, 0, 0, 0, 0};
        for (int j = 0; j < 8; ++j)
            for (int e = 0; e < 8; ++e) acc[e] += red[j][threadIdx.x][e];
        for (int e = 0; e < 4; ++e) {
            part[((size_t)b * HD + threadIdx.x * 4 + e) * 2 + 0] = acc[e];
            part[((size_t)b * HD + threadIdx.x * 4 + e) * 2 + 1] = acc[4 + e];
        }
    }
}

__global__ void finalize_nhwc(const float* __restrict__ part, float* __restrict__ mean,
                              float* __restrict__ rstd) {
    int p = blockIdx.x * blockDim.x + threadIdx.x;
    if (p >= B * HD) return;
    int n = p >> 7, c = p & 127;
    float s = 0, q = 0;
    for (int ch = 0; ch < 64; ++ch) {
        s += part[((size_t)(n * 64 + ch) * HD + c) * 2 + 0];
        q += part[((size_t)(n * 64 + ch) * HD + c) * 2 + 1];
    }
    float m = s / (float)PLANE4;
    mean[p] = m;
    rstd[p] = rsqrtf(q / (float)PLANE4 - m * m + 1e-5f);
}

__global__ __launch_bounds__(256) void apply_nhwc(const float* __restrict__ zr,
                                                  u16* __restrict__ zb,
                                                  const float* __restrict__ mean,
                                                  const float* __restrict__ rstd) {
    int i4 = blockIdx.x * 256 + threadIdx.x;
    int c4 = (i4 & 31) * 4;
    int n = i4 / (T * F4 * 32);
    float4 v = *(const float4*)(zr + (size_t)i4 * 4);
    float4 m = *(const float4*)(mean + n * HD + c4);
    float4 r = *(const float4*)(rstd + n * HD + c4);
    u64 pk = (u64)f2bf((v.x - m.x) * r.x) | ((u64)f2bf((v.y - m.y) * r.y) << 16)
           | ((u64)f2bf((v.z - m.z) * r.z) << 32) | ((u64)f2bf((v.w - m.w) * r.w) << 48);
    *(u64*)(zb + (size_t)i4 * 4) = pk;
}

// ======================= instance norm, NCHW =======================
__global__ __launch_bounds__(256) void inorm_stats(const float* __restrict__ x,
                                                   float* __restrict__ part,
                                                   int plane, int nchunks) {
    int p = blockIdx.x / nchunks, c = blockIdx.x % nchunks;
    int len = plane / nchunks;
    const float4* xp = (const float4*)(x + (size_t)p * plane + (size_t)c * len);
    int n4 = len / 4;
    float s = 0.f, q = 0.f;
    for (int i = threadIdx.x; i < n4; i += 256) {
        float4 v = xp[i];
        s += v.x + v.y + v.z + v.w;
        q += v.x * v.x + v.y * v.y + v.z * v.z + v.w * v.w;
    }
#pragma unroll
    for (int off = 32; off > 0; off >>= 1) {
        s += __shfl_down(s, off);
        q += __shfl_down(q, off);
    }
    __shared__ float ss[4], qq[4];
    int wid = threadIdx.x >> 6;
    if ((threadIdx.x & 63) == 0) { ss[wid] = s; qq[wid] = q; }
    __syncthreads();
    if (threadIdx.x == 0) {
        part[blockIdx.x * 2]     = ss[0] + ss[1] + ss[2] + ss[3];
        part[blockIdx.x * 2 + 1] = qq[0] + qq[1] + qq[2] + qq[3];
    }
}

__global__ void inorm_finalize(const float* __restrict__ part, float* __restrict__ mean,
                               float* __restrict__ rstd, int nplanes, int nchunks,
                               float inv_plane) {
    int p = blockIdx.x * blockDim.x + threadIdx.x;
    if (p >= nplanes) return;
    float s = 0.f, q = 0.f;
    for (int c = 0; c < nchunks; ++c) {
        s += part[(p * nchunks + c) * 2];
        q += part[(p * nchunks + c) * 2 + 1];
    }
    float m = s * inv_plane;
    mean[p] = m;
    rstd[p] = rsqrtf(q * inv_plane - m * m + 1e-5f);
}

template<int PSIZE>
__global__ __launch_bounds__(256) void inorm_apply(const float* __restrict__ in,
                                                   float* __restrict__ out,
                                                   const float* __restrict__ mean,
                                                   const float* __restrict__ rstd) {
    int i4 = blockIdx.x * 256 + threadIdx.x;
    int p = (i4 * 4) / PSIZE;
    float m = mean[p], r = rstd[p];
    float4 v = ((const float4*)in)[i4];
    v.x = (v.x - m) * r; v.y = (v.y - m) * r; v.z = (v.z - m) * r; v.w = (v.w - m) * r;
    ((float4*)out)[i4] = v;
}

// ======================= launcher =======================
extern "C" void kernel_launch(void* const* d_in, const int* in_sizes, int n_in,
                              void* d_out, int out_size, void* d_ws, size_t ws_size,
                              hipStream_t stream) {
    (void)in_sizes; (void)n_in; (void)out_size; (void)ws_size;
    const float* cqt  = (const float*)d_in[0];
    const float* w0   = (const float*)d_in[1];  const float* b0  = (const float*)d_in[2];
    const float* w1   = (const float*)d_in[3];  const float* b1  = (const float*)d_in[4];
    const float* w2   = (const float*)d_in[5];  const float* b2  = (const float*)d_in[6];
    const float* w_hd = (const float*)d_in[7];  const float* bhd = (const float*)d_in[8];
    const float* wd0  = (const float*)d_in[9];  const float* bd0 = (const float*)d_in[10];
    const float* wd1  = (const float*)d_in[11]; const float* bd1 = (const float*)d_in[12];
    const float* wd2  = (const float*)d_in[13]; const float* bd2 = (const float*)d_in[14];
    const float* wd3  = (const float*)d_in[15]; const float* bd3 = (const float*)d_in[16];
    const float* wd4  = (const float*)d_in[17]; const float* bd4 = (const float*)d_in[18];
    float* zr = (float*)d_out;   // d_out: conv-stack scratch, NHWC z scratch, final out

    // workspace (~93.3 MB, same extent as round 6)
    float* x1   = (float*)d_ws;                               // 11,534,336 f (hd input)
    u16*   zb16 = (u16*)(x1 + (size_t)B * CF * PLANE);        // region2: 23,068,672 u16
    u16*   xb   = zb16;   // padded fp16 NHWC conv buffer (11,796,480 u16) — dead before zb16 live
    u16*   packW = zb16 + (size_t)23068672 + 2048;
    u16*   WpP  = packW;                                      // 36,864
    u16*   wd0P = WpP  + 36864;                               // 49,152
    u16*   wd1P = wd0P + 49152;
    u16*   wd2P = wd1P + 49152;                               // 81,920
    u16*   wd3P = wd2P + 81920;
    u16*   wd4P = wd3P + 81920;
    u16*   c7aP = wd4P + 81920;                               // 14,336
    u16*   c7bP = c7aP + 14336;                               // 14,336
    float* bsum = (float*)(c7bP + 14336);                     // 128
    float* part = bsum + 128;                                 // 65,536
    float* meanb = part + 65536;                              // 512
    float* rstdb = meanb + 512;                               // 512

    // weight packing
    prep_hd_pack<<<18, 256, 0, stream>>>(w_hd, bhd, WpP, bsum);
    pack_wd<<<24, 256, 0, stream>>>(wd0, wd0P, 3, 12);
    pack_wd<<<24, 256, 0, stream>>>(wd1, wd1P, 3, 12);
    pack_wd<<<40, 256, 0, stream>>>(wd2, wd2P, 5, 20);
    pack_wd<<<40, 256, 0, stream>>>(wd3, wd3P, 5, 20);
    pack_wd<<<40, 256, 0, stream>>>(wd4, wd4P, 5, 20);
    pack_c7<<<7, 256, 0, stream>>>(w1, c7aP);
    pack_c7<<<7, 256, 0, stream>>>(w2, c7bP);

    auto stats_big = [&](float* bin) {
        inorm_stats<<<64 * 8, 256, 0, stream>>>(bin, part, PLANE, 8);
        inorm_finalize<<<1, 64, 0, stream>>>(part, meanb, rstdb, 64, 8, 1.f / PLANE);
    };
    auto norm_nhwc = [&]() {
        stats_nhwc<<<256, 256, 0, stream>>>(zr, part);
        finalize_nhwc<<<2, 256, 0, stream>>>(part, meanb, rstdb);
        apply_nhwc<<<B * T * F4 * HD / 4 / 256, 256, 0, stream>>>(zr, zb16, meanb, rstdb);
    };

    // cnn stack: conv -> stats -> apply(xb fp16 | x1 fp32)
    conv7x7_c1<<<B * T * F / 256, 256, 0, stream>>>(cqt, w0, b0, zr);
    stats_big(zr);
    apply_xb<0><<<B * T, 256, 0, stream>>>(zr, xb, nullptr, meanb, rstdb);
    conv7_mfma<<<B * T, 256, 0, stream>>>(xb, c7aP, b1, zr);
    stats_big(zr);
    apply_xb<0><<<B * T, 256, 0, stream>>>(zr, xb, nullptr, meanb, rstdb);
    conv7_mfma<<<B * T, 256, 0, stream>>>(xb, c7bP, b2, zr);
    stats_big(zr);
    apply_xb<1><<<B * T, 256, 0, stream>>>(zr, nullptr, x1, meanb, rstdb);

    // fused hd + wd0 + relu + pool (MFMA): x1 -> zr (NHWC fp32)
    hipFuncSetAttribute((const void*)hd_wd0_mfma,
                        hipFuncAttributeMaxDynamicSharedMemorySize, 147456);
    hd_wd0_mfma<<<B * T, 512, 146944, stream>>>(x1, WpP, wd0P, bsum, bd0, zr);
    norm_nhwc();

    wd1_mfma<<<B * T, 256, 0, stream>>>(zb16, wd1P, bd1, zr);
    norm_nhwc();
    wd5_mfma<false><<<B * T, 256, 0, stream>>>(zb16, wd2P, bd2, zr);
    norm_nhwc();
    wd5_mfma<false><<<B * T, 256, 0, stream>>>(zb16, wd3P, bd3, zr);
    norm_nhwc();
    wd5_mfma<true><<<B * T, 256, 0, stream>>>(zb16, wd4P, bd4, zr);  // NCHW out

    inorm_stats<<<512 * 4, 256, 0, stream>>>(zr, part, PLANE4, 4);
    inorm_finalize<<<1, 512, 0, stream>>>(part, meanb, rstdb, 512, 4, 1.f / PLANE4);
    inorm_apply<PLANE4><<<512 * PLANE4 / 4 / 256, 256, 0, stream>>>(zr, zr, meanb, rstdb);
}

// Round 12
// 1133.419 us; speedup vs baseline: 11.2604x; 1.0514x over previous
//
#include <hip/hip_runtime.h>
#include <hip/hip_bf16.h>

constexpr int B = 4, T = 512, F = 352, CF = 16, HD = 128, F4 = 88;
constexpr int PLANE  = T * F;    // 180224
constexpr int PLANE4 = T * F4;   // 45056
constexpr int NDIL = 8;
constexpr int FP  = 360;         // xb padded width (f' = f+3)
constexpr int XBP = 760, XPAD = 208;   // xbf padded width for hd conv (f' = f+208)

typedef __attribute__((ext_vector_type(8))) short short8;
typedef __attribute__((ext_vector_type(8))) _Float16 half8;
typedef __attribute__((ext_vector_type(4))) _Float16 half4;
typedef __attribute__((ext_vector_type(4))) float f32x4;
typedef unsigned short u16;
typedef unsigned long long u64;

#define MFMA(a, b, c)   __builtin_amdgcn_mfma_f32_16x16x32_bf16(a, b, c, 0, 0, 0)
#define MFMA16(a, b, c) __builtin_amdgcn_mfma_f32_16x16x32_f16(a, b, c, 0, 0, 0)

__device__ inline u16 f2bf(float x) {
    unsigned u = __float_as_uint(x);
    return (u16)((u + 0x7fffu + ((u >> 16) & 1u)) >> 16);
}
__device__ inline u16 f2h(float x) {
    _Float16 h = (_Float16)x;
    u16 r; __builtin_memcpy(&r, &h, 2);
    return r;
}

// ======================= weight packing =======================
__global__ void prep_hd_pack(const float* __restrict__ w_hd, const float* __restrict__ b_hd,
                             u16* __restrict__ WpP, float* __restrict__ bsum) {
    int tid = blockIdx.x * 256 + threadIdx.x;
    if (tid < HD) {
        float s = 0.f;
        for (int d = 0; d < NDIL; ++d) s += b_hd[d * HD + tid];
        bsum[tid] = s;
    }
    if (tid >= 8 * 9 * 64) return;
    int l = tid & 63, c = (tid >> 6) % 9, og = tid / (9 * 64);
    int cout = og * 16 + (l & 15);
#pragma unroll
    for (int e = 0; e < 8; ++e) {
        int k = c * 32 + ((l >> 4) * 8) + e;
        int tau = k >> 4, ci = k & 15;
        float v = 0.f;
        if (tau == 0) {
            for (int d = 0; d < NDIL; ++d) v += w_hd[((d * HD + cout) * CF + ci) * 3 + 1];
        } else if (tau <= 8) {
            v = w_hd[(((tau - 1) * HD + cout) * CF + ci) * 3 + 0];
        } else if (tau <= 16) {
            v = w_hd[(((tau - 9) * HD + cout) * CF + ci) * 3 + 2];
        }
        WpP[tid * 8 + e] = f2bf(v);
    }
}

__global__ void pack_wd(const float* __restrict__ wsrc, u16* __restrict__ dst,
                        int ntap, int nch) {
    int tid = blockIdx.x * 256 + threadIdx.x;
    if (tid >= 8 * nch * 64) return;
    int l = tid & 63, c = (tid >> 6) % nch, og = tid / (nch * 64);
    int cout = og * 16 + (l & 15);
#pragma unroll
    for (int e = 0; e < 8; ++e) {
        int k = c * 32 + ((l >> 4) * 8) + e;
        int tau = k >> 7, ci = k & 127;
        float v = (tau < ntap) ? wsrc[(cout * HD + ci) * ntap + tau] : 0.f;
        dst[tid * 8 + e] = f2bf(v);
    }
}

__global__ void pack_c7(const float* __restrict__ wsrc, u16* __restrict__ dst) {
    int tid = blockIdx.x * 256 + threadIdx.x;
    if (tid >= 28 * 64) return;
    int l = tid & 63, c = tid >> 6;
    int cout = l & 15, g = l >> 4;
#pragma unroll
    for (int e = 0; e < 8; ++e) {
        int k = c * 32 + g * 8 + e;
        int taup = k >> 4, ci = k & 15;
        int dy = taup >> 3, dx = taup & 7;
        float v = (dx < 7) ? wsrc[((cout * CF + ci) * 7 + dy) * 7 + dx] : 0.f;
        dst[tid * 8 + e] = f2h(v);
    }
}

// ======================= conv0 (CIN=1, fp32 VALU) -> fp16 NHWC =======================
__global__ __launch_bounds__(256) void conv7x7_c1(
        const float* __restrict__ x, const float* __restrict__ w,
        const float* __restrict__ bias, u16* __restrict__ zc) {
    int idx = blockIdx.x * 256 + threadIdx.x;
    int f = idx % F;
    int t = (idx / F) % T;
    int n = idx / (F * T);
    float acc[CF];
#pragma unroll
    for (int co = 0; co < CF; ++co) acc[co] = bias[co];
    const float* xp = x + n * PLANE;
    float xv[49];
#pragma unroll
    for (int dy = 0; dy < 7; ++dy) {
        int tt = t + dy - 3;
        bool tok = (unsigned)tt < (unsigned)T;
#pragma unroll
        for (int dx = 0; dx < 7; ++dx) {
            int ff = f + dx - 3;
            xv[dy * 7 + dx] = (tok && (unsigned)ff < (unsigned)F) ? xp[tt * F + ff] : 0.f;
        }
    }
#pragma unroll
    for (int co = 0; co < CF; ++co) {
        const float* wpc = w + co * 49;
#pragma unroll
        for (int k = 0; k < 49; ++k) acc[co] = fmaf(xv[k], wpc[k], acc[co]);
    }
    u64 pk[4];
    u16* ph = (u16*)pk;
#pragma unroll
    for (int co = 0; co < CF; ++co) ph[co] = f2h(fmaxf(acc[co], 0.f));
    u64* op = (u64*)(zc + ((size_t)(n * T + t) * F + f) * 16);
#pragma unroll
    for (int qd = 0; qd < 4; ++qd) op[qd] = pk[qd];
}

// ======================= conv1/conv2: 7x7 MFMA fp16, direct-global B -> fp16 NHWC =======================
__global__ __launch_bounds__(256) void conv7_mfma(
        const u16* __restrict__ xb, const u16* __restrict__ wP,
        const float* __restrict__ bias, u16* __restrict__ zc) {
    const int n = blockIdx.x / T, t = blockIdx.x % T;
    const int l = threadIdx.x & 63, w = threadIdx.x >> 6;
    const int g = l >> 4;
    f32x4 acc[6];
    {
        f32x4 b4 = *(const f32x4*)(bias + g * 4);
#pragma unroll
        for (int i = 0; i < 6; ++i) acc[i] = b4;
    }
    for (int c = 0; c < 28; ++c) {
        int trow = t + (c >> 2) - 3;
        if ((unsigned)trow >= (unsigned)T) continue;
        half8 A = *(const half8*)(wP + c * 512 + l * 8);
        int dx = 2 * (c & 3) + (g >> 1);
        const u16* brow = xb + (size_t)(n * T + trow) * FP * 16;
#pragma unroll
        for (int i = 0; i < 6; ++i) {
            int ft = w + 4 * i;
            if (ft < 22) {
                int fcol = ft * 16 + (l & 15) + dx;
                half8 Bv = *(const half8*)(brow + fcol * 16 + (g & 1) * 8);
                acc[i] = MFMA16(A, Bv, acc[i]);
            }
        }
    }
#pragma unroll
    for (int i = 0; i < 6; ++i) {
        int ft = w + 4 * i;
        if (ft < 22) {
            int f = ft * 16 + (l & 15);
            u64 pk;
            u16* ph = (u16*)&pk;
#pragma unroll
            for (int r = 0; r < 4; ++r) ph[r] = f2h(fmaxf(acc[i][r], 0.f));
            *(u64*)(zc + ((size_t)(n * T + t) * F + f) * 16 + g * 4) = pk;
        }
    }
}

// ======================= cnn-stack instance norm (fp16 NHWC-16) =======================
__global__ __launch_bounds__(256) void stats_c16(const u16* __restrict__ zc,
                                                 float* __restrict__ part) {
    int b = blockIdx.x;                  // B*32
    int n = b >> 5, ch = b & 31;
    int cgrp = threadIdx.x & 3, rt = threadIdx.x >> 2;
    int l = threadIdx.x & 63, wid = threadIdx.x >> 6;
    const u16* bp = zc + ((size_t)n * PLANE + ch * 5632) * 16 + cgrp * 4;
    float s[4] = {0, 0, 0, 0}, q[4] = {0, 0, 0, 0};
    for (int k = 0; k < 88; ++k) {
        half4 v = *(const half4*)(bp + (size_t)(rt + 64 * k) * 16);
#pragma unroll
        for (int e = 0; e < 4; ++e) { float x = (float)v[e]; s[e] += x; q[e] += x * x; }
    }
#pragma unroll
    for (int off = 32; off >= 4; off >>= 1) {
#pragma unroll
        for (int e = 0; e < 4; ++e) { s[e] += __shfl_down(s[e], off); q[e] += __shfl_down(q[e], off); }
    }
    __shared__ float red[4][4][8];
    if (l < 4) {
#pragma unroll
        for (int e = 0; e < 4; ++e) { red[wid][l][e] = s[e]; red[wid][l][4 + e] = q[e]; }
    }
    __syncthreads();
    if (threadIdx.x < 4) {
        float a[8] = {0, 0, 0, 0, 0, 0, 0, 0};
        for (int w2 = 0; w2 < 4; ++w2)
            for (int e = 0; e < 8; ++e) a[e] += red[w2][threadIdx.x][e];
#pragma unroll
        for (int e = 0; e < 4; ++e) {
            part[((size_t)b * 16 + threadIdx.x * 4 + e) * 2 + 0] = a[e];
            part[((size_t)b * 16 + threadIdx.x * 4 + e) * 2 + 1] = a[4 + e];
        }
    }
}

__global__ void finalize_c16(const float* __restrict__ part, float* __restrict__ mean,
                             float* __restrict__ rstd) {
    int p = threadIdx.x;
    if (p >= B * CF) return;
    int n = p >> 4, c = p & 15;
    float s = 0, q = 0;
    for (int ch = 0; ch < 32; ++ch) {
        s += part[(((size_t)(n * 32 + ch)) * 16 + c) * 2 + 0];
        q += part[(((size_t)(n * 32 + ch)) * 16 + c) * 2 + 1];
    }
    float m = s / (float)PLANE;
    mean[p] = m;
    rstd[p] = rsqrtf(q / (float)PLANE - m * m + 1e-5f);
}

// MODE 0: write fp16 normalized padded xb (FP,+3); MODE 1: write bf16 normalized padded xbf (XBP,+208)
template<int MODE>
__global__ __launch_bounds__(256) void apply_cnn(
        const u16* __restrict__ zc, u16* __restrict__ dst,
        const float* __restrict__ mean, const float* __restrict__ rstd) {
    const int n = blockIdx.x / T, t = blockIdx.x % T;
    const int tid = threadIdx.x;
    float m[CF], r[CF];
#pragma unroll
    for (int ci = 0; ci < CF; ++ci) { m[ci] = mean[n * CF + ci]; r[ci] = rstd[n * CF + ci]; }
    u16* drow = dst + (size_t)(n * T + t) * (MODE ? XBP : FP) * 16;
    if (MODE == 0) {
        if (tid < 32) {
            int colIdx = tid >> 2;
            int col = colIdx < 3 ? colIdx : 352 + colIdx;   // {0,1,2,355..359}
            *(u64*)(drow + col * 16 + (tid & 3) * 4) = 0ULL;
        }
    } else {
#pragma unroll
        for (int k = 0; k < 7; ++k) {
            int idx = tid + k * 256;
            if (idx < 1632) {                               // 408 guard cols * 4 u64
                int colIdx = idx >> 2;
                int col = colIdx < XPAD ? colIdx : colIdx + 352;   // [0,208) U [560,760)
                *(u64*)(drow + col * 16 + (idx & 3) * 4) = 0ULL;
            }
        }
    }
    const u16* srow = zc + (size_t)(n * T + t) * F * 16;
    for (int f = tid; f < F; f += 256) {
        const half4* ip = (const half4*)(srow + (size_t)f * 16);
        u64 ov[4];
        u16* oh = (u16*)ov;
#pragma unroll
        for (int qd = 0; qd < 4; ++qd) {
            half4 v = ip[qd];
#pragma unroll
            for (int e = 0; e < 4; ++e) {
                int ci = qd * 4 + e;
                float x = ((float)v[e] - m[ci]) * r[ci];
                oh[ci] = MODE ? f2bf(x) : f2h(x);
            }
        }
        u64* op = (u64*)(drow + (size_t)(f + (MODE ? XPAD : 3)) * 16);
#pragma unroll
        for (int qd = 0; qd < 4; ++qd) op[qd] = ov[qd];
    }
}

// ======================= fused hd + wd0 + relu + pool, MFMA, split f-halves =======================
// grid = B*T*2 (h fastest). LDS = yT only: 272 rows x 256 B = 69632 B -> 2 WG/CU.
// Phase-1 B-fragments read global xbf (padded bf16 NHWC-16).
__global__ __launch_bounds__(512, 4) void hd_wd0_mfma(
        const u16* __restrict__ xbf, const u16* __restrict__ WpP,
        const u16* __restrict__ wd0P, const float* __restrict__ bsum,
        const float* __restrict__ bd0, u16* __restrict__ zr16) {
    extern __shared__ char yT[];             // swizzled, local row = f_global - ybase
    const int h = blockIdx.x & 1;
    const int nt = blockIdx.x >> 1;
    const int n = nt / T, t = nt % T;
    const int tid = threadIdx.x, l = tid & 63, wid = tid >> 6;
    const int quad = wid & 1, fq = wid >> 1;
    const int g = l >> 4;
    const int ybase = h ? 128 : -48;         // global f of local row 0
    const int comp0 = h ? 128 : 0;           // first computed y col

    // zero guard rows: h0 local [0,48); h1 local [224,272)
    {
        int base = h ? 224 * 256 : 0;
#pragma unroll
        for (int k = 0; k < 3; ++k)
            *(u64*)(yT + base + (tid + k * 512) * 8) = 0ULL;
    }

    // ---- phase 1: y = hd conv (K=288), B from global xbf ----
    f32x4 acc[4][4];
#pragma unroll
    for (int og4 = 0; og4 < 4; ++og4) {
        f32x4 b4 = *(const f32x4*)(bsum + (quad * 4 + og4) * 16 + g * 4);
#pragma unroll
        for (int i = 0; i < 4; ++i) acc[i][og4] = b4;
    }
    const int OFFA[9] = {0, -76, -111, -135, -152, 76, 111, 135, 152};
    const int OFFB[9] = {-48, -96, -124, -144, 48, 96, 124, 144, 0};
    const u16* xrow = xbf + (size_t)(n * T + t) * XBP * 16;
#pragma unroll
    for (int c = 0; c < 9; ++c) {
        short8 A[4];
#pragma unroll
        for (int og4 = 0; og4 < 4; ++og4)
            A[og4] = *(const short8*)(WpP + ((quad * 4 + og4) * 9 + c) * 512 + l * 8);
        int off = (l >> 5) ? OFFB[c] : OFFA[c];
#pragma unroll
        for (int i = 0; i < 4; ++i) {
            int ft = fq + 4 * i;
            if (ft < 14) {
                int f = comp0 + ft * 16 + (l & 15);
                short8 Bv = *(const short8*)(xrow + (size_t)(f + off + XPAD) * 16 + (g & 1) * 8);
#pragma unroll
                for (int og4 = 0; og4 < 4; ++og4) acc[i][og4] = MFMA(A[og4], Bv, acc[i][og4]);
            }
        }
    }
    // write yT (bf16, swizzled on local row)
#pragma unroll
    for (int i = 0; i < 4; ++i) {
        int ft = fq + 4 * i;
        if (ft < 14) {
            int lrow = (comp0 + ft * 16 + (l & 15)) - ybase;
#pragma unroll
            for (int og4 = 0; og4 < 4; ++og4) {
                int cb = ((quad * 4 + og4) * 16 + g * 4) * 2;
                u64 pk = (u64)f2bf(acc[i][og4][0]) | ((u64)f2bf(acc[i][og4][1]) << 16)
                       | ((u64)f2bf(acc[i][og4][2]) << 32) | ((u64)f2bf(acc[i][og4][3]) << 48);
                *(u64*)(yT + lrow * 256 + (cb ^ ((lrow & 7) << 4))) = pk;
            }
        }
    }
    __syncthreads();

    // ---- phase 2: wd0 (K=384, taps -48/0/+48) + relu + pool4 -> fp16 NHWC ----
#pragma unroll
    for (int og4 = 0; og4 < 4; ++og4) {
        f32x4 b4 = *(const f32x4*)(bd0 + (quad * 4 + og4) * 16 + g * 4);
#pragma unroll
        for (int i = 0; i < 3; ++i) acc[i][og4] = b4;
    }
#pragma unroll
    for (int c = 0; c < 12; ++c) {
        short8 A[4];
#pragma unroll
        for (int og4 = 0; og4 < 4; ++og4)
            A[og4] = *(const short8*)(wd0P + ((quad * 4 + og4) * 12 + c) * 512 + l * 8);
        int off = (c >> 2) * 48 - 48;
        int cib = (c & 3) * 64 + g * 16;
#pragma unroll
        for (int i = 0; i < 3; ++i) {
            int ft = fq + 4 * i;
            if (ft < 11) {
                int lr = (h * 176 + ft * 16 + (l & 15)) + off - ybase;
                short8 Bv = *(const short8*)(yT + lr * 256 + (cib ^ ((lr & 7) << 4)));
#pragma unroll
                for (int og4 = 0; og4 < 4; ++og4) acc[i][og4] = MFMA(A[og4], Bv, acc[i][og4]);
            }
        }
    }
#pragma unroll
    for (int i = 0; i < 3; ++i) {
        int ft = fq + 4 * i;
        if (ft < 11) {
#pragma unroll
            for (int og4 = 0; og4 < 4; ++og4) {
                u64 pk;
                u16* ph = (u16*)&pk;
#pragma unroll
                for (int r = 0; r < 4; ++r) {
                    float a = fmaxf(acc[i][og4][r], 0.f);
                    a = fmaxf(a, __shfl_xor(a, 1));
                    a = fmaxf(a, __shfl_xor(a, 2));
                    ph[r] = f2h(a);
                }
                if ((l & 3) == 0) {
                    int fp = (h * 176 + ft * 16 + (l & 15)) >> 2;
                    int cout0 = (quad * 4 + og4) * 16 + g * 4;
                    *(u64*)(zr16 + ((size_t)(n * T + t) * F4 + fp) * HD + cout0) = pk;
                }
            }
        }
    }
}

// ======================= wd1: 1x3 dil12, MFMA, LDS-staged -> fp16 NHWC =======================
__global__ __launch_bounds__(256) void wd1_mfma(
        const u16* __restrict__ zb, const u16* __restrict__ wP,
        const float* __restrict__ bias, u16* __restrict__ out) {
    __shared__ char lds[128 * 256];
    const int n = blockIdx.x / T, t = blockIdx.x % T;
    const int tid = threadIdx.x, l = tid & 63, w = tid >> 6;
    const int g = l >> 4;
    {
        int cib = (tid & 15) * 16;
        int fi = tid >> 4;
        const u16* src = zb + (size_t)(n * T + t) * F4 * HD;
#pragma unroll
        for (int k = 0; k < 6; ++k) {
            int f = fi + 16 * k;
            if (f < F4) {
                short8 v = *(const short8*)(src + f * HD + (tid & 15) * 8);
                *(short8*)(lds + (f + 16) * 256 + (cib ^ ((f & 7) << 4))) = v;
            }
        }
#pragma unroll
        for (int k = 0; k < 3; ++k) {
            int idx = tid + k * 256;
            if (idx < 640) {
                int row = idx >> 4, slot = idx & 15;
                int arow = row < 16 ? row : row + 88;
                *(u64*)(lds + arow * 256 + slot * 16) = 0ULL;
                *(u64*)(lds + arow * 256 + slot * 16 + 8) = 0ULL;
            }
        }
    }
    __syncthreads();
    f32x4 acc[6][2];
#pragma unroll
    for (int og2 = 0; og2 < 2; ++og2) {
        f32x4 b4 = *(const f32x4*)(bias + (w * 2 + og2) * 16 + g * 4);
#pragma unroll
        for (int i = 0; i < 6; ++i) acc[i][og2] = b4;
    }
#pragma unroll
    for (int c = 0; c < 12; ++c) {
        short8 A0 = *(const short8*)(wP + ((w * 2 + 0) * 12 + c) * 512 + l * 8);
        short8 A1 = *(const short8*)(wP + ((w * 2 + 1) * 12 + c) * 512 + l * 8);
        int off = (c >> 2) * 12 - 12;
        int cib = (c & 3) * 64 + g * 16;
#pragma unroll
        for (int i = 0; i < 6; ++i) {
            int fr = i * 16 + (l & 15) + off;
            short8 Bv = *(const short8*)(lds + (fr + 16) * 256 + (cib ^ ((fr & 7) << 4)));
            acc[i][0] = MFMA(A0, Bv, acc[i][0]);
            acc[i][1] = MFMA(A1, Bv, acc[i][1]);
        }
    }
#pragma unroll
    for (int i = 0; i < 6; ++i) {
        int f = i * 16 + (l & 15);
        if (f < F4) {
#pragma unroll
            for (int og2 = 0; og2 < 2; ++og2) {
                int cout0 = (w * 2 + og2) * 16 + g * 4;
                u64 pk;
                u16* ph = (u16*)&pk;
#pragma unroll
                for (int r = 0; r < 4; ++r) ph[r] = f2h(fmaxf(acc[i][og2][r], 0.f));
                *(u64*)(out + ((size_t)(n * T + t) * F4 + f) * HD + cout0) = pk;
            }
        }
    }
}

// ======================= wd2/3/4: 5x1 time conv, MFMA, direct-global B -> fp16 =======================
template<bool NCHW_OUT>
__global__ __launch_bounds__(256) void wd5_mfma(
        const u16* __restrict__ zb, const u16* __restrict__ wP,
        const float* __restrict__ bias, u16* __restrict__ out) {
    const int n = blockIdx.x / T, t = blockIdx.x % T;
    const int tid = threadIdx.x, l = tid & 63, w = tid >> 6;
    const int g = l >> 4;
    f32x4 acc[6][2];
#pragma unroll
    for (int og2 = 0; og2 < 2; ++og2) {
        f32x4 b4 = *(const f32x4*)(bias + (w * 2 + og2) * 16 + g * 4);
#pragma unroll
        for (int i = 0; i < 6; ++i) acc[i][og2] = b4;
    }
#pragma unroll
    for (int c = 0; c < 20; ++c) {
        int trow = t + (c >> 2) - 2;
        if ((unsigned)trow < (unsigned)T) {
            short8 A0 = *(const short8*)(wP + ((w * 2 + 0) * 20 + c) * 512 + l * 8);
            short8 A1 = *(const short8*)(wP + ((w * 2 + 1) * 20 + c) * 512 + l * 8);
            int cio = (c & 3) * 32 + g * 8;
            const u16* brow = zb + (size_t)(n * T + trow) * F4 * HD;
#pragma unroll
            for (int i = 0; i < 6; ++i) {
                int f = i * 16 + (l & 15);
                short8 Bv = *(const short8*)(brow + f * HD + cio);
                acc[i][0] = MFMA(A0, Bv, acc[i][0]);
                acc[i][1] = MFMA(A1, Bv, acc[i][1]);
            }
        }
    }
#pragma unroll
    for (int i = 0; i < 6; ++i) {
        int f = i * 16 + (l & 15);
        if (f < F4) {
#pragma unroll
            for (int og2 = 0; og2 < 2; ++og2) {
                int cout0 = (w * 2 + og2) * 16 + g * 4;
                if (NCHW_OUT) {
#pragma unroll
                    for (int r = 0; r < 4; ++r)
                        out[((size_t)(n * HD + cout0 + r) * T + t) * F4 + f] =
                            f2h(fmaxf(acc[i][og2][r], 0.f));
                } else {
                    u64 pk;
                    u16* ph = (u16*)&pk;
#pragma unroll
                    for (int r = 0; r < 4; ++r) ph[r] = f2h(fmaxf(acc[i][og2][r], 0.f));
                    *(u64*)(out + ((size_t)(n * T + t) * F4 + f) * HD + cout0) = pk;
                }
            }
        }
    }
}

// ======================= z-chain instance norm (fp16 NHWC-128) =======================
__global__ __launch_bounds__(256) void stats_c128(const u16* __restrict__ zr16,
                                                  float* __restrict__ part) {
    int b = blockIdx.x;                  // 256: n = b>>6, chunk = b&63 (8 t-rows each)
    int n = b >> 6, ch = b & 63;
    int c4 = (threadIdx.x & 31) * 4;
    int rg = threadIdx.x >> 5;
    int row = ch * 8 + rg;
    const u16* rp = zr16 + ((size_t)(n * T + row) * F4) * HD + c4;
    float s0 = 0, s1 = 0, s2 = 0, s3 = 0, q0 = 0, q1 = 0, q2 = 0, q3 = 0;
    for (int f = 0; f < F4; ++f) {
        half4 v = *(const half4*)(rp + (size_t)f * HD);
        float x0 = (float)v[0], x1 = (float)v[1], x2 = (float)v[2], x3 = (float)v[3];
        s0 += x0; s1 += x1; s2 += x2; s3 += x3;
        q0 += x0 * x0; q1 += x1 * x1; q2 += x2 * x2; q3 += x3 * x3;
    }
    __shared__ float red[8][32][8];
    float* rr = red[rg][threadIdx.x & 31];
    rr[0] = s0; rr[1] = s1; rr[2] = s2; rr[3] = s3;
    rr[4] = q0; rr[5] = q1; rr[6] = q2; rr[7] = q3;
    __syncthreads();
    if (threadIdx.x < 32) {
        float acc[8] = {0, 0, 0, 0, 0, 0, 0, 0};
        for (int j = 0; j < 8; ++j)
            for (int e = 0; e < 8; ++e) acc[e] += red[j][threadIdx.x][e];
        for (int e = 0; e < 4; ++e) {
            part[((size_t)b * HD + threadIdx.x * 4 + e) * 2 + 0] = acc[e];
            part[((size_t)b * HD + threadIdx.x * 4 + e) * 2 + 1] = acc[4 + e];
        }
    }
}

__global__ void finalize_nhwc(const float* __restrict__ part, float* __restrict__ mean,
                              float* __restrict__ rstd) {
    int p = blockIdx.x * blockDim.x + threadIdx.x;
    if (p >= B * HD) return;
    int n = p >> 7, c = p & 127;
    float s = 0, q = 0;
    for (int ch = 0; ch < 64; ++ch) {
        s += part[((size_t)(n * 64 + ch) * HD + c) * 2 + 0];
        q += part[((size_t)(n * 64 + ch) * HD + c) * 2 + 1];
    }
    float m = s / (float)PLANE4;
    mean[p] = m;
    rstd[p] = rsqrtf(q / (float)PLANE4 - m * m + 1e-5f);
}

__global__ __launch_bounds__(256) void apply_z(const u16* __restrict__ zr16,
                                               u16* __restrict__ zb,
                                               const float* __restrict__ mean,
                                               const float* __restrict__ rstd) {
    int i8 = blockIdx.x * 256 + threadIdx.x;     // over total/8 = 2,883,584
    int c8 = (i8 & 15) * 8;
    int n = i8 / (T * F4 * 16);
    half8 hv = *(const half8*)(zr16 + (size_t)i8 * 8);
    const float* mp = mean + n * HD + c8;
    const float* rp = rstd + n * HD + c8;
    short8 o;
#pragma unroll
    for (int e = 0; e < 8; ++e)
        o[e] = (short)f2bf(((float)hv[e] - mp[e]) * rp[e]);
    *(short8*)(zb + (size_t)i8 * 8) = o;
}

// ======================= final instance norm (fp16 NCHW -> fp32) =======================
__global__ __launch_bounds__(256) void stats_nchw16(const u16* __restrict__ x,
                                                    float* __restrict__ part) {
    int p = blockIdx.x >> 2, c = blockIdx.x & 3;
    const u16* xp = x + (size_t)p * PLANE4 + c * 11264;
    float s = 0.f, q = 0.f;
    for (int i = threadIdx.x; i < 1408; i += 256) {
        half8 v = *(const half8*)(xp + (size_t)i * 8);
#pragma unroll
        for (int e = 0; e < 8; ++e) { float xx = (float)v[e]; s += xx; q += xx * xx; }
    }
#pragma unroll
    for (int off = 32; off > 0; off >>= 1) {
        s += __shfl_down(s, off);
        q += __shfl_down(q, off);
    }
    __shared__ float ss[4], qq[4];
    int wid = threadIdx.x >> 6;
    if ((threadIdx.x & 63) == 0) { ss[wid] = s; qq[wid] = q; }
    __syncthreads();
    if (threadIdx.x == 0) {
        part[blockIdx.x * 2]     = ss[0] + ss[1] + ss[2] + ss[3];
        part[blockIdx.x * 2 + 1] = qq[0] + qq[1] + qq[2] + qq[3];
    }
}

__global__ void inorm_finalize(const float* __restrict__ part, float* __restrict__ mean,
                               float* __restrict__ rstd, int nplanes, int nchunks,
                               float inv_plane) {
    int p = blockIdx.x * blockDim.x + threadIdx.x;
    if (p >= nplanes) return;
    float s = 0.f, q = 0.f;
    for (int c = 0; c < nchunks; ++c) {
        s += part[(p * nchunks + c) * 2];
        q += part[(p * nchunks + c) * 2 + 1];
    }
    float m = s * inv_plane;
    mean[p] = m;
    rstd[p] = rsqrtf(q * inv_plane - m * m + 1e-5f);
}

__global__ __launch_bounds__(256) void apply_nchw16(const u16* __restrict__ x,
                                                    float* __restrict__ out,
                                                    const float* __restrict__ mean,
                                                    const float* __restrict__ rstd) {
    int i8 = blockIdx.x * 256 + threadIdx.x;
    int p = (int)(((long long)i8 * 8) / PLANE4);
    float m = mean[p], r = rstd[p];
    half8 v = *(const half8*)(x + (size_t)i8 * 8);
    f32x4 o0, o1;
#pragma unroll
    for (int e = 0; e < 4; ++e) o0[e] = ((float)v[e] - m) * r;
#pragma unroll
    for (int e = 0; e < 4; ++e) o1[e] = ((float)v[4 + e] - m) * r;
    *(f32x4*)(out + (size_t)i8 * 8) = o0;
    *(f32x4*)(out + (size_t)i8 * 8 + 4) = o1;
}

// ======================= launcher =======================
extern "C" void kernel_launch(void* const* d_in, const int* in_sizes, int n_in,
                              void* d_out, int out_size, void* d_ws, size_t ws_size,
                              hipStream_t stream) {
    (void)in_sizes; (void)n_in; (void)out_size; (void)ws_size;
    const float* cqt  = (const float*)d_in[0];
    const float* w0   = (const float*)d_in[1];  const float* b0  = (const float*)d_in[2];
    const float* w1   = (const float*)d_in[3];  const float* b1  = (const float*)d_in[4];
    const float* w2   = (const float*)d_in[5];  const float* b2  = (const float*)d_in[6];
    const float* w_hd = (const float*)d_in[7];  const float* bhd = (const float*)d_in[8];
    const float* wd0  = (const float*)d_in[9];  const float* bd0 = (const float*)d_in[10];
    const float* wd1  = (const float*)d_in[11]; const float* bd1 = (const float*)d_in[12];
    const float* wd2  = (const float*)d_in[13]; const float* bd2 = (const float*)d_in[14];
    const float* wd3  = (const float*)d_in[15]; const float* bd3 = (const float*)d_in[16];
    const float* wd4  = (const float*)d_in[17]; const float* bd4 = (const float*)d_in[18];

    // ---- workspace (~97 MB) ----
    u16* xbf  = (u16*)d_ws;                     // B*T*760*16 = 24,903,680 u16 (hd input)
    u16* zz16 = xbf;                            // alias: wd4 fp16 NCHW out (23,068,672) — xbf dead
    u16* zb16 = xbf + 24903680;                 // 23,068,672 u16 (normalized bf16 NHWC z)
    u16* WpP  = zb16 + 23068672;                // 36,864
    u16* wd0P = WpP  + 36864;                   // 49,152
    u16* wd1P = wd0P + 49152;
    u16* wd2P = wd1P + 49152;                   // 81,920
    u16* wd3P = wd2P + 81920;
    u16* wd4P = wd3P + 81920;
    u16* c7aP = wd4P + 81920;                   // 14,336
    u16* c7bP = c7aP + 14336;
    float* bsum  = (float*)(c7bP + 14336);      // 128
    float* part  = bsum + 128;                  // 65,536
    float* meanb = part + 65536;                // 512
    float* rstdb = meanb + 512;                 // 512

    // ---- d_out staging (92 MB capacity) ----
    u16* zdo  = (u16*)d_out;
    u16* zc   = zdo;                            // cnn pre-norm fp16 NHWC (11,534,336)
    u16* xb   = zdo + 11534336;                 // cnn normalized fp16 padded (11,796,480)
    u16* zr16 = zdo;                            // z pre-norm fp16 NHWC (23,068,672) — zc/xb dead
    float* outf = (float*)d_out;                // final fp32 (reads zz16 in ws)

    // weight packing
    prep_hd_pack<<<18, 256, 0, stream>>>(w_hd, bhd, WpP, bsum);
    pack_wd<<<24, 256, 0, stream>>>(wd0, wd0P, 3, 12);
    pack_wd<<<24, 256, 0, stream>>>(wd1, wd1P, 3, 12);
    pack_wd<<<40, 256, 0, stream>>>(wd2, wd2P, 5, 20);
    pack_wd<<<40, 256, 0, stream>>>(wd3, wd3P, 5, 20);
    pack_wd<<<40, 256, 0, stream>>>(wd4, wd4P, 5, 20);
    pack_c7<<<7, 256, 0, stream>>>(w1, c7aP);
    pack_c7<<<7, 256, 0, stream>>>(w2, c7bP);

    auto norm_cnn16 = [&](int mode) {   // zc -> (xb | xbf)
        stats_c16<<<B * 32, 256, 0, stream>>>(zc, part);
        finalize_c16<<<1, 64, 0, stream>>>(part, meanb, rstdb);
        if (mode == 0) apply_cnn<0><<<B * T, 256, 0, stream>>>(zc, xb, meanb, rstdb);
        else           apply_cnn<1><<<B * T, 256, 0, stream>>>(zc, xbf, meanb, rstdb);
    };
    auto norm_z = [&]() {               // zr16 -> zb16
        stats_c128<<<256, 256, 0, stream>>>(zr16, part);
        finalize_nhwc<<<2, 256, 0, stream>>>(part, meanb, rstdb);
        apply_z<<<11264, 256, 0, stream>>>(zr16, zb16, meanb, rstdb);
    };

    // cnn stack
    conv7x7_c1<<<B * T * F / 256, 256, 0, stream>>>(cqt, w0, b0, zc);
    norm_cnn16(0);
    conv7_mfma<<<B * T, 256, 0, stream>>>(xb, c7aP, b1, zc);
    norm_cnn16(0);
    conv7_mfma<<<B * T, 256, 0, stream>>>(xb, c7bP, b2, zc);
    norm_cnn16(1);                      // -> xbf (bf16 padded, hd input)

    // fused hd + wd0 + relu + pool
    hipFuncSetAttribute((const void*)hd_wd0_mfma,
                        hipFuncAttributeMaxDynamicSharedMemorySize, 69632);
    hd_wd0_mfma<<<B * T * 2, 512, 69632, stream>>>(xbf, WpP, wd0P, bsum, bd0, zr16);
    norm_z();

    wd1_mfma<<<B * T, 256, 0, stream>>>(zb16, wd1P, bd1, zr16);
    norm_z();
    wd5_mfma<false><<<B * T, 256, 0, stream>>>(zb16, wd2P, bd2, zr16);
    norm_z();
    wd5_mfma<false><<<B * T, 256, 0, stream>>>(zb16, wd3P, bd3, zr16);
    norm_z();
    wd5_mfma<true><<<B * T, 256, 0, stream>>>(zb16, wd4P, bd4, zz16);   // fp16 NCHW (ws)

    stats_nchw16<<<B * HD * 4, 256, 0, stream>>>(zz16, part);
    inorm_finalize<<<2, 256, 0, stream>>>(part, meanb, rstdb, 512, 4, 1.f / PLANE4);
    apply_nchw16<<<11264, 256, 0, stream>>>(zz16, outf, meanb, rstdb);
}